// Round 1
// 707.911 us; speedup vs baseline: 1.2509x; 1.2509x over previous
//
#include <hip/hip_runtime.h>
#include <math.h>

#define F0 512
#define F1 16
#define F2 40
#define SB 128          // rows per super-bucket
#define SB_SHIFT 7
#define COL_BITS 17     // n <= 131072
#define NG 8            // XCD groups
#define NG_SHIFT 3
#define CAP 768         // slots per (super-bucket, group) cell; mean 512, +11 sigma

__global__ void k_zero(int* p, int m) {
    int i = blockIdx.x * blockDim.x + threadIdx.x;
    if (i < m) p[i] = 0;
}

// ---------------- pass A: direct scatter into fixed-capacity (sb, group) cells ----
// group = blockIdx & 7 matches the round-robin block->XCD mapping, so all writes
// to a given tail line come from one XCD's L2 -> full-line writebacks. 6256 cells
// (vs 25000 before) keep every tail line hot in L2 until all 16 entries land.
__global__ __launch_bounds__(256) void k_fill1(const int* __restrict__ row,
                                               const int* __restrict__ col, int E,
                                               int* cnt, int* __restrict__ ebuf) {
    int g = blockIdx.x & (NG - 1);
    int base = (blockIdx.x * blockDim.x + threadIdx.x) * 4;
    if (base + 3 < E) {
        int4 r4 = *(const int4*)(row + base);
        int4 c4 = *(const int4*)(col + base);
        int rr[4] = {r4.x, r4.y, r4.z, r4.w};
        int cc[4] = {c4.x, c4.y, c4.z, c4.w};
#pragma unroll
        for (int q = 0; q < 4; q++) {
            int cell = ((rr[q] >> SB_SHIFT) << NG_SHIFT) | g;
            int p = atomicAdd(&cnt[cell], 1);
            ebuf[cell * CAP + p] = ((rr[q] & (SB - 1)) << COL_BITS) | cc[q];
        }
    } else {
        for (int e = base; e < E; e++) {
            int r = row[e], c = col[e];
            int cell = ((r >> SB_SHIFT) << NG_SHIFT) | g;
            int p = atomicAdd(&cnt[cell], 1);
            ebuf[cell * CAP + p] = ((r & (SB - 1)) << COL_BITS) | c;
        }
    }
}

// ---------------- pass B: exclusive scan of per-super-bucket totals --------------
// NSB <= 1024 for n <= 131072.
__global__ __launch_bounds__(1024) void k_scan(const int* __restrict__ cnt, int NSB,
                                               int* __restrict__ sbbase) {
    __shared__ int part[1024];
    int t = threadIdx.x;
    int total = 0;
    if (t < NSB) {
#pragma unroll
        for (int g = 0; g < NG; g++) total += cnt[(t << NG_SHIFT) + g];
    }
    part[t] = total;
    __syncthreads();
    for (int off = 1; off < 1024; off <<= 1) {
        int a = (t >= off) ? part[t - off] : 0;
        __syncthreads();
        part[t] += a;
        __syncthreads();
    }
    if (t < NSB) sbbase[t] = part[t] - total;  // exclusive
}

// ---------------- pass C: per-super-bucket counting sort -> colsort, deg, rs, dinv
__global__ __launch_bounds__(256) void k_sort2(const int* __restrict__ cnt,
                                               const int* __restrict__ sbbase,
                                               const int* __restrict__ ebuf, int n,
                                               int* __restrict__ colsort,
                                               int* __restrict__ deg,
                                               int* __restrict__ rs,
                                               float* __restrict__ dinv) {
    __shared__ int rcnt[SB];
    __shared__ int rexcl[SB];
    __shared__ int gcnt[NG];
    int sb = blockIdx.x;
    int t = threadIdx.x;
    if (t < SB) rcnt[t] = 0;
    if (t < NG) gcnt[t] = cnt[(sb << NG_SHIFT) + t];
    __syncthreads();
    // pass 1: count rows
    for (int g = 0; g < NG; g++) {
        int c = gcnt[g];
        const int* seg = ebuf + ((sb << NG_SHIFT) + g) * CAP;
        for (int e = t; e < c; e += 256)
            atomicAdd(&rcnt[seg[e] >> COL_BITS], 1);
    }
    __syncthreads();
    if (t == 0) {
        int run = 0;
        for (int r = 0; r < SB; r++) { rexcl[r] = run; run += rcnt[r]; }
    }
    __syncthreads();
    int base = sbbase[sb];
    if (t < SB) {
        int i = (sb << SB_SHIFT) + t;
        if (i < n) {
            deg[i] = rcnt[t];
            rs[i] = base + rexcl[t];
            dinv[i] = rsqrtf((float)(rcnt[t] + 1));
        }
        rcnt[t] = rexcl[t];  // reuse as cursor
    }
    __syncthreads();
    // pass 2: scatter (block-local L2 range -> good locality)
    for (int g = 0; g < NG; g++) {
        int c = gcnt[g];
        const int* seg = ebuf + ((sb << NG_SHIFT) + g) * CAP;
        for (int e = t; e < c; e += 256) {
            int v = seg[e];
            int p = atomicAdd(&rcnt[v >> COL_BITS], 1);
            colsort[base + p] = v & ((1 << COL_BITS) - 1);
        }
    }
}

// ---------------- GEMM1: hp[i][j] = dinv[i] * (x[i,:] @ W1[:,j]) ----------------
__global__ __launch_bounds__(256) void k_gemm1(const float* __restrict__ x,
                                               const float* __restrict__ W1,
                                               const float* __restrict__ dinv,
                                               float* __restrict__ hp, int n,
                                               int total_waves) {
    int lane = threadIdx.x & 63;
    int wid = blockIdx.x * (blockDim.x >> 6) + (threadIdx.x >> 6);

    float w[8][16];
#pragma unroll
    for (int h = 0; h < 2; h++) {
#pragma unroll
        for (int r = 0; r < 4; r++) {
            int k = h * 256 + 4 * lane + r;
            const float4* p = (const float4*)(W1 + k * 16);
            float4 a = p[0], b = p[1], c = p[2], d = p[3];
            float* wr = w[h * 4 + r];
            wr[0] = a.x; wr[1] = a.y; wr[2] = a.z; wr[3] = a.w;
            wr[4] = b.x; wr[5] = b.y; wr[6] = b.z; wr[7] = b.w;
            wr[8] = c.x; wr[9] = c.y; wr[10] = c.z; wr[11] = c.w;
            wr[12] = d.x; wr[13] = d.y; wr[14] = d.z; wr[15] = d.w;
        }
    }

    for (int i = wid; i < n; i += total_waves) {
        const float4* xp = (const float4*)(x + (size_t)i * F0);
        float4 xa = xp[lane];
        float4 xb = xp[64 + lane];
        float acc[16];
#pragma unroll
        for (int j = 0; j < 16; j++) {
            acc[j] = xa.x * w[0][j] + xa.y * w[1][j] + xa.z * w[2][j] + xa.w * w[3][j]
                   + xb.x * w[4][j] + xb.y * w[5][j] + xb.z * w[6][j] + xb.w * w[7][j];
        }
#pragma unroll
        for (int j = 0; j < 16; j++) {
            float v = acc[j];
            v += __shfl_xor(v, 1);
            v += __shfl_xor(v, 2);
            v += __shfl_xor(v, 4);
            v += __shfl_xor(v, 8);
            v += __shfl_xor(v, 16);
            v += __shfl_xor(v, 32);
            acc[j] = v;
        }
        if (lane < 16) {
            float v = acc[0];
#pragma unroll
            for (int j = 1; j < 16; j++) v = (lane == j) ? acc[j] : v;
            hp[(size_t)i * F1 + lane] = dinv[i] * v;
        }
    }
}

// ---------------- SpMM1 + relu, store s2 = dinv * h1 (16 feats) ----------------
__global__ __launch_bounds__(256) void k_spmm1(const float* __restrict__ hp,
                                               const int* __restrict__ rs,
                                               const int* __restrict__ deg,
                                               const int* __restrict__ colsort,
                                               const float* __restrict__ dinv,
                                               const float* __restrict__ b1,
                                               float* __restrict__ s2, int n) {
    int t = threadIdx.x;
    int lane = t & 63;
    int g = lane >> 4;
    int jf = lane & 15;
    int i = blockIdx.x * 4 + (t >> 6);
    if (i >= n) return;
    int s = rs[i], c = deg[i];
    float acc = (g == 0) ? hp[(size_t)i * F1 + jf] : 0.f;
    int e = g;
    for (; e + 4 < c; e += 8) {
        int c0 = colsort[s + e];
        int c1 = colsort[s + e + 4];
        float v0 = hp[(size_t)c0 * F1 + jf];
        float v1 = hp[(size_t)c1 * F1 + jf];
        acc += v0 + v1;
    }
    if (e < c) acc += hp[(size_t)colsort[s + e] * F1 + jf];
    acc += __shfl_xor(acc, 16);
    acc += __shfl_xor(acc, 32);
    float di = dinv[i];
    float h1 = fmaxf(di * acc + b1[jf], 0.f);
    if (lane < 16) s2[(size_t)i * F1 + jf] = di * h1;
}

// ---------------- SpMM2 (16 feats) + GEMM2 + bias + log_softmax ----------------
__global__ __launch_bounds__(256) void k_spmm2(const float* __restrict__ s2,
                                               const int* __restrict__ rs,
                                               const int* __restrict__ deg,
                                               const int* __restrict__ colsort,
                                               const float* __restrict__ dinv,
                                               const float* __restrict__ W2,
                                               const float* __restrict__ b2,
                                               float* __restrict__ out, int n) {
    __shared__ float sW2[F1 * F2];
    int t = threadIdx.x;
    for (int idx = t; idx < F1 * F2; idx += 256) sW2[idx] = W2[idx];
    __syncthreads();

    int lane = t & 63;
    int g = lane >> 4;
    int jf = lane & 15;
    int i = blockIdx.x * 4 + (t >> 6);
    if (i >= n) return;
    int s = rs[i], c = deg[i];
    float acc = (g == 0) ? s2[(size_t)i * F1 + jf] : 0.f;
    int e = g;
    for (; e + 4 < c; e += 8) {
        int c0 = colsort[s + e];
        int c1 = colsort[s + e + 4];
        float v0 = s2[(size_t)c0 * F1 + jf];
        float v1 = s2[(size_t)c1 * F1 + jf];
        acc += v0 + v1;
    }
    if (e < c) acc += s2[(size_t)colsort[s + e] * F1 + jf];
    acc += __shfl_xor(acc, 16);
    acc += __shfl_xor(acc, 32);
    float z = dinv[i] * acc;

    bool act = lane < F2;
    int k = act ? lane : 0;
    float o = 0.f;
#pragma unroll
    for (int j = 0; j < F1; j++) {
        float zj = __shfl(z, j);
        o += zj * sW2[j * F2 + k];
    }
    float val = act ? o + b2[k] : -INFINITY;
    float m = val;
#pragma unroll
    for (int off = 1; off < 64; off <<= 1) m = fmaxf(m, __shfl_xor(m, off));
    float ex = act ? __expf(val - m) : 0.f;
    float ssum = ex;
#pragma unroll
    for (int off = 1; off < 64; off <<= 1) ssum += __shfl_xor(ssum, off);
    if (act) out[(size_t)i * F2 + lane] = val - m - __logf(ssum);
}

extern "C" void kernel_launch(void* const* d_in, const int* in_sizes, int n_in,
                              void* d_out, int out_size, void* d_ws, size_t ws_size,
                              hipStream_t stream) {
    const float* x  = (const float*)d_in[0];
    const float* W1 = (const float*)d_in[1];
    const float* b1 = (const float*)d_in[2];
    const float* W2 = (const float*)d_in[3];
    const float* b2 = (const float*)d_in[4];
    const int*   ei = (const int*)d_in[5];

    int n = in_sizes[0] / F0;
    int E = in_sizes[5] / 2;
    const int* row = ei;
    const int* col = ei + E;
    int NSB = (n + SB - 1) >> SB_SHIFT;   // 782 for n=100000
    int NCELL = NSB << NG_SHIFT;          // 6256

    // workspace carve-up (4-byte elements)
    int* deg     = (int*)d_ws;            // n
    int* rs      = deg + n;               // n
    float* dinv  = (float*)(rs + n);      // n
    int* cnt     = (int*)(dinv + n);      // NCELL
    int* sbbase  = cnt + NCELL;           // NSB
    int* colsort = sbbase + NSB;          // E
    int* ebuf    = colsort + E;           // NCELL*CAP (~19.2 MB) — dead after k_sort2
    float* hp    = (float*)ebuf;          // n x 16 (overlay on ebuf)
    float* s2    = hp + (size_t)n * F1;   // n x 16 (overlay on ebuf)

    k_zero<<<(NCELL + 255) / 256, 256, 0, stream>>>(cnt, NCELL);
    k_fill1<<<(E + 1023) / 1024, 256, 0, stream>>>(row, col, E, cnt, ebuf);
    k_scan<<<1, 1024, 0, stream>>>(cnt, NSB, sbbase);
    k_sort2<<<NSB, 256, 0, stream>>>(cnt, sbbase, ebuf, n, colsort, deg, rs, dinv);

    int g1_blocks = 2048;
    k_gemm1<<<g1_blocks, 256, 0, stream>>>(x, W1, dinv, hp, n, g1_blocks * 4);
    k_spmm1<<<(n + 3) / 4, 256, 0, stream>>>(hp, rs, deg, colsort, dinv, b1, s2, n);
    k_spmm2<<<(n + 3) / 4, 256, 0, stream>>>(s2, rs, deg, colsort, dinv, W2, b2,
                                             (float*)d_out, n);
}

// Round 2
// 650.959 us; speedup vs baseline: 1.3604x; 1.0875x over previous
//
#include <hip/hip_runtime.h>
#include <math.h>

#define F0 512
#define F1 16
#define F2 40
#define SB 128          // rows per super-bucket
#define SB_SHIFT 7
#define COL_BITS 17     // n <= 131072
#define NG 8            // XCD groups
#define NG_SHIFT 3
#define CAP 768         // slots per (super-bucket, group) cell; mean 512, +11 sigma

__global__ void k_zero(int* p, int m) {
    int i = blockIdx.x * blockDim.x + threadIdx.x;
    if (i < m) p[i] = 0;
}

// ---------------- pass A: direct scatter into fixed-capacity (sb, group) cells ----
__global__ __launch_bounds__(256) void k_fill1(const int* __restrict__ row,
                                               const int* __restrict__ col, int E,
                                               int* cnt, int* __restrict__ ebuf) {
    int g = blockIdx.x & (NG - 1);
    int base = (blockIdx.x * blockDim.x + threadIdx.x) * 4;
    if (base + 3 < E) {
        int4 r4 = *(const int4*)(row + base);
        int4 c4 = *(const int4*)(col + base);
        int rr[4] = {r4.x, r4.y, r4.z, r4.w};
        int cc[4] = {c4.x, c4.y, c4.z, c4.w};
#pragma unroll
        for (int q = 0; q < 4; q++) {
            int cell = ((rr[q] >> SB_SHIFT) << NG_SHIFT) | g;
            int p = atomicAdd(&cnt[cell], 1);
            ebuf[cell * CAP + p] = ((rr[q] & (SB - 1)) << COL_BITS) | cc[q];
        }
    } else {
        for (int e = base; e < E; e++) {
            int r = row[e], c = col[e];
            int cell = ((r >> SB_SHIFT) << NG_SHIFT) | g;
            int p = atomicAdd(&cnt[cell], 1);
            ebuf[cell * CAP + p] = ((r & (SB - 1)) << COL_BITS) | c;
        }
    }
}

// ---------------- pass B: exclusive scan of per-super-bucket totals --------------
__global__ __launch_bounds__(1024) void k_scan(const int* __restrict__ cnt, int NSB,
                                               int* __restrict__ sbbase) {
    __shared__ int part[1024];
    int t = threadIdx.x;
    int total = 0;
    if (t < NSB) {
#pragma unroll
        for (int g = 0; g < NG; g++) total += cnt[(t << NG_SHIFT) + g];
    }
    part[t] = total;
    __syncthreads();
    for (int off = 1; off < 1024; off <<= 1) {
        int a = (t >= off) ? part[t - off] : 0;
        __syncthreads();
        part[t] += a;
        __syncthreads();
    }
    if (t < NSB) sbbase[t] = part[t] - total;  // exclusive
}

// ---------------- pass C: per-super-bucket counting sort -> colsort, deg, rs, dinv
__global__ __launch_bounds__(256) void k_sort2(const int* __restrict__ cnt,
                                               const int* __restrict__ sbbase,
                                               const int* __restrict__ ebuf, int n,
                                               int* __restrict__ colsort,
                                               int* __restrict__ deg,
                                               int* __restrict__ rs,
                                               float* __restrict__ dinv) {
    __shared__ int rcnt[SB];
    __shared__ int rexcl[SB];
    __shared__ int gcnt[NG];
    int sb = blockIdx.x;
    int t = threadIdx.x;
    if (t < SB) rcnt[t] = 0;
    if (t < NG) gcnt[t] = cnt[(sb << NG_SHIFT) + t];
    __syncthreads();
    for (int g = 0; g < NG; g++) {
        int c = gcnt[g];
        const int* seg = ebuf + ((sb << NG_SHIFT) + g) * CAP;
        for (int e = t; e < c; e += 256)
            atomicAdd(&rcnt[seg[e] >> COL_BITS], 1);
    }
    __syncthreads();
    if (t == 0) {
        int run = 0;
        for (int r = 0; r < SB; r++) { rexcl[r] = run; run += rcnt[r]; }
    }
    __syncthreads();
    int base = sbbase[sb];
    if (t < SB) {
        int i = (sb << SB_SHIFT) + t;
        if (i < n) {
            deg[i] = rcnt[t];
            rs[i] = base + rexcl[t];
            dinv[i] = rsqrtf((float)(rcnt[t] + 1));
        }
        rcnt[t] = rexcl[t];  // reuse as cursor
    }
    __syncthreads();
    for (int g = 0; g < NG; g++) {
        int c = gcnt[g];
        const int* seg = ebuf + ((sb << NG_SHIFT) + g) * CAP;
        for (int e = t; e < c; e += 256) {
            int v = seg[e];
            int p = atomicAdd(&rcnt[v >> COL_BITS], 1);
            colsort[base + p] = v & ((1 << COL_BITS) - 1);
        }
    }
}

// ---------------- GEMM1: hp[i][j] = dinv[i] * (x[i,:] @ W1[:,j]) ----------------
// 4 rows per wave per iteration (8 independent float4 loads in flight),
// w[8][16] held resident (launch_bounds(256,2) -> 256 VGPR cap),
// split-tree butterfly reduce: 15 shfl/row, result lands in lane==column.
__global__ __launch_bounds__(256, 2) void k_gemm1(const float* __restrict__ x,
                                                  const float* __restrict__ W1,
                                                  const float* __restrict__ dinv,
                                                  float* __restrict__ hp, int n,
                                                  int total_waves) {
    int lane = threadIdx.x & 63;
    int wid = blockIdx.x * (blockDim.x >> 6) + (threadIdx.x >> 6);

    // per-lane weight slice: k in {4*lane..+3} U {256+4*lane..+3}
    float w[8][16];
#pragma unroll
    for (int h = 0; h < 2; h++) {
#pragma unroll
        for (int r = 0; r < 4; r++) {
            int k = h * 256 + 4 * lane + r;
            const float4* p = (const float4*)(W1 + k * 16);
            float4 a = p[0], b = p[1], c = p[2], d = p[3];
            float* wr = w[h * 4 + r];
            wr[0] = a.x; wr[1] = a.y; wr[2] = a.z; wr[3] = a.w;
            wr[4] = b.x; wr[5] = b.y; wr[6] = b.z; wr[7] = b.w;
            wr[8] = c.x; wr[9] = c.y; wr[10] = c.z; wr[11] = c.w;
            wr[12] = d.x; wr[13] = d.y; wr[14] = d.z; wr[15] = d.w;
        }
    }

    for (int i0 = wid * 4; i0 < n; i0 += total_waves * 4) {
        float4 xq[8];
        if (i0 + 3 < n) {
            // 4 consecutive rows = 512 contiguous float4; 8 coalesced passes
            const float4* xp = (const float4*)(x + (size_t)i0 * F0);
#pragma unroll
            for (int q = 0; q < 8; q++) xq[q] = xp[q * 64 + lane];
        } else {
#pragma unroll
            for (int q = 0; q < 8; q++) {
                int r = q >> 1;
                if (i0 + r < n) {
                    const float4* xp = (const float4*)(x + (size_t)(i0 + r) * F0);
                    xq[q] = xp[(q & 1) * 64 + lane];
                } else {
                    xq[q] = make_float4(0.f, 0.f, 0.f, 0.f);
                }
            }
        }
        bool b0 = (lane & 1) != 0;
        bool b1 = (lane & 2) != 0;
        bool b2 = (lane & 4) != 0;
        bool b3 = (lane & 8) != 0;
#pragma unroll
        for (int r = 0; r < 4; r++) {
            float4 xa = xq[2 * r], xb = xq[2 * r + 1];
            float v16[16];
#pragma unroll
            for (int j = 0; j < 16; j++) {
                v16[j] = xa.x * w[0][j] + xa.y * w[1][j] + xa.z * w[2][j] + xa.w * w[3][j]
                       + xb.x * w[4][j] + xb.y * w[5][j] + xb.z * w[6][j] + xb.w * w[7][j];
            }
            // butterfly with value-splitting: 16->8->4->2->1 values/lane
            float v8[8];
#pragma unroll
            for (int t2 = 0; t2 < 8; t2++) {
                float a = v16[2 * t2], b = v16[2 * t2 + 1];
                float keep = b0 ? b : a;
                float send = b0 ? a : b;
                v8[t2] = keep + __shfl_xor(send, 1);
            }
            float v4[4];
#pragma unroll
            for (int t2 = 0; t2 < 4; t2++) {
                float a = v8[2 * t2], b = v8[2 * t2 + 1];
                float keep = b1 ? b : a;
                float send = b1 ? a : b;
                v4[t2] = keep + __shfl_xor(send, 2);
            }
            float v2[2];
#pragma unroll
            for (int t2 = 0; t2 < 2; t2++) {
                float a = v4[2 * t2], b = v4[2 * t2 + 1];
                float keep = b2 ? b : a;
                float send = b2 ? a : b;
                v2[t2] = keep + __shfl_xor(send, 4);
            }
            float keep = b3 ? v2[1] : v2[0];
            float send = b3 ? v2[0] : v2[1];
            float v1 = keep + __shfl_xor(send, 8);
            // v1 = column (lane&15), summed within 16-lane group
            v1 += __shfl_xor(v1, 16);
            v1 += __shfl_xor(v1, 32);
            int i = i0 + r;
            if (lane < 16 && i < n)
                hp[(size_t)i * F1 + lane] = dinv[i] * v1;
        }
    }
}

// ---------------- SpMM1 + relu, store s2 = dinv * h1 (16 feats) ----------------
__global__ __launch_bounds__(256) void k_spmm1(const float* __restrict__ hp,
                                               const int* __restrict__ rs,
                                               const int* __restrict__ deg,
                                               const int* __restrict__ colsort,
                                               const float* __restrict__ dinv,
                                               const float* __restrict__ b1,
                                               float* __restrict__ s2, int n) {
    int t = threadIdx.x;
    int lane = t & 63;
    int g = lane >> 4;
    int jf = lane & 15;
    int i = blockIdx.x * 4 + (t >> 6);
    if (i >= n) return;
    int s = rs[i], c = deg[i];
    float acc = (g == 0) ? hp[(size_t)i * F1 + jf] : 0.f;
    int e = g;
    for (; e + 4 < c; e += 8) {
        int c0 = colsort[s + e];
        int c1 = colsort[s + e + 4];
        float v0 = hp[(size_t)c0 * F1 + jf];
        float v1 = hp[(size_t)c1 * F1 + jf];
        acc += v0 + v1;
    }
    if (e < c) acc += hp[(size_t)colsort[s + e] * F1 + jf];
    acc += __shfl_xor(acc, 16);
    acc += __shfl_xor(acc, 32);
    float di = dinv[i];
    float h1 = fmaxf(di * acc + b1[jf], 0.f);
    if (lane < 16) s2[(size_t)i * F1 + jf] = di * h1;
}

// ---------------- SpMM2 (16 feats) + GEMM2 + bias + log_softmax ----------------
__global__ __launch_bounds__(256) void k_spmm2(const float* __restrict__ s2,
                                               const int* __restrict__ rs,
                                               const int* __restrict__ deg,
                                               const int* __restrict__ colsort,
                                               const float* __restrict__ dinv,
                                               const float* __restrict__ W2,
                                               const float* __restrict__ b2,
                                               float* __restrict__ out, int n) {
    __shared__ float sW2[F1 * F2];
    int t = threadIdx.x;
    for (int idx = t; idx < F1 * F2; idx += 256) sW2[idx] = W2[idx];
    __syncthreads();

    int lane = t & 63;
    int g = lane >> 4;
    int jf = lane & 15;
    int i = blockIdx.x * 4 + (t >> 6);
    if (i >= n) return;
    int s = rs[i], c = deg[i];
    float acc = (g == 0) ? s2[(size_t)i * F1 + jf] : 0.f;
    int e = g;
    for (; e + 4 < c; e += 8) {
        int c0 = colsort[s + e];
        int c1 = colsort[s + e + 4];
        float v0 = s2[(size_t)c0 * F1 + jf];
        float v1 = s2[(size_t)c1 * F1 + jf];
        acc += v0 + v1;
    }
    if (e < c) acc += s2[(size_t)colsort[s + e] * F1 + jf];
    acc += __shfl_xor(acc, 16);
    acc += __shfl_xor(acc, 32);
    float z = dinv[i] * acc;

    bool act = lane < F2;
    int k = act ? lane : 0;
    float o = 0.f;
#pragma unroll
    for (int j = 0; j < F1; j++) {
        float zj = __shfl(z, j);
        o += zj * sW2[j * F2 + k];
    }
    float val = act ? o + b2[k] : -INFINITY;
    float m = val;
#pragma unroll
    for (int off = 1; off < 64; off <<= 1) m = fmaxf(m, __shfl_xor(m, off));
    float ex = act ? __expf(val - m) : 0.f;
    float ssum = ex;
#pragma unroll
    for (int off = 1; off < 64; off <<= 1) ssum += __shfl_xor(ssum, off);
    if (act) out[(size_t)i * F2 + lane] = val - m - __logf(ssum);
}

extern "C" void kernel_launch(void* const* d_in, const int* in_sizes, int n_in,
                              void* d_out, int out_size, void* d_ws, size_t ws_size,
                              hipStream_t stream) {
    const float* x  = (const float*)d_in[0];
    const float* W1 = (const float*)d_in[1];
    const float* b1 = (const float*)d_in[2];
    const float* W2 = (const float*)d_in[3];
    const float* b2 = (const float*)d_in[4];
    const int*   ei = (const int*)d_in[5];

    int n = in_sizes[0] / F0;
    int E = in_sizes[5] / 2;
    const int* row = ei;
    const int* col = ei + E;
    int NSB = (n + SB - 1) >> SB_SHIFT;   // 782 for n=100000
    int NCELL = NSB << NG_SHIFT;          // 6256

    // workspace carve-up (4-byte elements)
    int* deg     = (int*)d_ws;            // n
    int* rs      = deg + n;               // n
    float* dinv  = (float*)(rs + n);      // n
    int* cnt     = (int*)(dinv + n);      // NCELL
    int* sbbase  = cnt + NCELL;           // NSB
    int* colsort = sbbase + NSB;          // E
    int* ebuf    = colsort + E;           // NCELL*CAP (~19.2 MB) — dead after k_sort2
    float* hp    = (float*)ebuf;          // n x 16 (overlay on ebuf)
    float* s2    = hp + (size_t)n * F1;   // n x 16 (overlay on ebuf)

    k_zero<<<(NCELL + 255) / 256, 256, 0, stream>>>(cnt, NCELL);
    k_fill1<<<(E + 1023) / 1024, 256, 0, stream>>>(row, col, E, cnt, ebuf);
    k_scan<<<1, 1024, 0, stream>>>(cnt, NSB, sbbase);
    k_sort2<<<NSB, 256, 0, stream>>>(cnt, sbbase, ebuf, n, colsort, deg, rs, dinv);

    int g1_blocks = 2048;
    k_gemm1<<<g1_blocks, 256, 0, stream>>>(x, W1, dinv, hp, n, g1_blocks * 4);
    k_spmm1<<<(n + 3) / 4, 256, 0, stream>>>(hp, rs, deg, colsort, dinv, b1, s2, n);
    k_spmm2<<<(n + 3) / 4, 256, 0, stream>>>(s2, rs, deg, colsort, dinv, W2, b2,
                                             (float*)d_out, n);
}

// Round 3
// 501.286 us; speedup vs baseline: 1.7665x; 1.2986x over previous
//
#include <hip/hip_runtime.h>
#include <math.h>

#define F0 512
#define F1 16
#define F2 40
#define CB_SHIFT 8          // 256 rows per coarse bucket
#define CB_ROWS 256
#define NCB_MAX 512         // n <= 131072
#define CAPCB 9216          // slots per bucket; mean 8184 at E=3.2M,NCB=391 (+11 sigma)
#define EPB 8192            // edges per fill block
#define COL_BITS 17         // n <= 131072
#define CMASK ((1 << COL_BITS) - 1)
#define CNT_STRIDE 16       // one 64B line per global bucket counter

__global__ void k_zero(int* p, int m) {
    int i = blockIdx.x * blockDim.x + threadIdx.x;
    if (i < m) p[i] = 0;
}

// ---- pass A: per-block counting sort of 8192 edges by coarse bucket; one global
// atomic per (block,bucket); all global stores coalesced runs. No scattered VMEM.
__global__ __launch_bounds__(512) void k_fill(const int* __restrict__ row,
                                              const int* __restrict__ col, int E,
                                              int* cnt, int* __restrict__ ebuf,
                                              int NCB) {
    __shared__ int hcnt[NCB_MAX];   // per-bucket count, then scatter cursor
    __shared__ int lexcl[NCB_MAX];  // block-local exclusive offsets
    __shared__ int hbase[NCB_MAX];  // reserved global base per bucket
    __shared__ int part[NCB_MAX];
    __shared__ int sorted[EPB];
    int t = threadIdx.x;
    int e0 = blockIdx.x * EPB;
    int nloc = min(EPB, E - e0);
    if (t < NCB_MAX) hcnt[t] = 0;
    __syncthreads();

    // load up to 16 edges into registers (4x int4 rows + 4x int4 cols)
    int rr[16], cc[16];
#pragma unroll
    for (int k = 0; k < 4; k++) {
        int base = t * 4 + k * 2048;
        if (base + 3 < nloc) {
            int4 r4 = *(const int4*)(row + e0 + base);
            int4 c4 = *(const int4*)(col + e0 + base);
            rr[k * 4 + 0] = r4.x; rr[k * 4 + 1] = r4.y;
            rr[k * 4 + 2] = r4.z; rr[k * 4 + 3] = r4.w;
            cc[k * 4 + 0] = c4.x; cc[k * 4 + 1] = c4.y;
            cc[k * 4 + 2] = c4.z; cc[k * 4 + 3] = c4.w;
        } else {
#pragma unroll
            for (int q = 0; q < 4; q++) {
                int e = base + q;
                rr[k * 4 + q] = (e < nloc) ? row[e0 + e] : -1;
                cc[k * 4 + q] = (e < nloc) ? col[e0 + e] : 0;
            }
        }
    }
    // histogram by coarse bucket (LDS atomics)
#pragma unroll
    for (int q = 0; q < 16; q++)
        if (rr[q] >= 0) atomicAdd(&hcnt[rr[q] >> CB_SHIFT], 1);
    __syncthreads();
    // exclusive scan over NCB_MAX entries (Hillis-Steele, 512 threads)
    int myv = hcnt[t];
    part[t] = myv;
    __syncthreads();
    for (int off = 1; off < NCB_MAX; off <<= 1) {
        int a = (t >= off) ? part[t - off] : 0;
        __syncthreads();
        part[t] += a;
        __syncthreads();
    }
    lexcl[t] = part[t] - myv;
    hbase[t] = (myv > 0) ? atomicAdd(&cnt[t * CNT_STRIDE], myv) : 0;
    hcnt[t] = 0;  // reset as cursor
    __syncthreads();
    // scatter into LDS-sorted buffer
#pragma unroll
    for (int q = 0; q < 16; q++) {
        int r = rr[q];
        if (r >= 0) {
            int cb = r >> CB_SHIFT;
            int p = lexcl[cb] + atomicAdd(&hcnt[cb], 1);
            sorted[p] = ((r & (CB_ROWS - 1)) << COL_BITS) | cc[q];
        }
    }
    __syncthreads();
    // copy runs out, one wave per bucket round-robin; coalesced stores
    int wv = t >> 6, lane = t & 63;
    for (int cb = wv; cb < NCB; cb += 8) {
        int c = hcnt[cb];
        int ls = lexcl[cb];
        int* dst = ebuf + (size_t)cb * CAPCB + hbase[cb];
        for (int j = lane; j < c; j += 64) dst[j] = sorted[ls + j];
    }
}

// ---- pass B: exclusive scan of bucket totals -> global CSR bases ----
__global__ __launch_bounds__(512) void k_scan2(const int* __restrict__ cnt, int NCB,
                                               int* __restrict__ sbbase) {
    __shared__ int part[NCB_MAX];
    int t = threadIdx.x;
    int v = (t < NCB) ? cnt[t * CNT_STRIDE] : 0;
    part[t] = v;
    __syncthreads();
    for (int off = 1; off < NCB_MAX; off <<= 1) {
        int a = (t >= off) ? part[t - off] : 0;
        __syncthreads();
        part[t] += a;
        __syncthreads();
    }
    if (t < NCB) sbbase[t] = part[t] - v;
}

// ---- pass C: per-bucket counting sort fully in LDS; coalesced colsort writes ----
__global__ __launch_bounds__(256) void k_sort(const int* __restrict__ cnt,
                                              const int* __restrict__ sbbase,
                                              const int* __restrict__ ebuf, int n,
                                              int* __restrict__ colsort,
                                              int* __restrict__ deg,
                                              int* __restrict__ rs,
                                              float* __restrict__ dinv) {
    __shared__ int rcnt[CB_ROWS];
    __shared__ int rexcl[CB_ROWS];
    __shared__ int sorted[CAPCB];
    int cb = blockIdx.x;
    int t = threadIdx.x;
    int c = cnt[cb * CNT_STRIDE];
    const int* seg = ebuf + (size_t)cb * CAPCB;
    rcnt[t] = 0;
    __syncthreads();
    // pass 1: count local rows
    for (int base = t * 4; base < c; base += 1024) {
        if (base + 3 < c) {
            int4 v = *(const int4*)(seg + base);
            atomicAdd(&rcnt[v.x >> COL_BITS], 1);
            atomicAdd(&rcnt[v.y >> COL_BITS], 1);
            atomicAdd(&rcnt[v.z >> COL_BITS], 1);
            atomicAdd(&rcnt[v.w >> COL_BITS], 1);
        } else {
            for (int k = base; k < c; k++) atomicAdd(&rcnt[seg[k] >> COL_BITS], 1);
        }
    }
    __syncthreads();
    int myc = rcnt[t];
    rexcl[t] = myc;
    __syncthreads();
    for (int off = 1; off < CB_ROWS; off <<= 1) {
        int a = (t >= off) ? rexcl[t - off] : 0;
        __syncthreads();
        rexcl[t] += a;
        __syncthreads();
    }
    int excl = rexcl[t] - myc;
    int gbase = sbbase[cb];
    int i = (cb << CB_SHIFT) + t;
    if (i < n) {
        deg[i] = myc;
        rs[i] = gbase + excl;
        dinv[i] = rsqrtf((float)(myc + 1));
    }
    rcnt[t] = excl;  // reuse as cursor
    __syncthreads();
    // pass 2: scatter into LDS-sorted buffer (seg is L2-hot)
    for (int base = t * 4; base < c; base += 1024) {
        if (base + 3 < c) {
            int4 v = *(const int4*)(seg + base);
            int p0 = atomicAdd(&rcnt[v.x >> COL_BITS], 1); sorted[p0] = v.x & CMASK;
            int p1 = atomicAdd(&rcnt[v.y >> COL_BITS], 1); sorted[p1] = v.y & CMASK;
            int p2 = atomicAdd(&rcnt[v.z >> COL_BITS], 1); sorted[p2] = v.z & CMASK;
            int p3 = atomicAdd(&rcnt[v.w >> COL_BITS], 1); sorted[p3] = v.w & CMASK;
        } else {
            for (int k = base; k < c; k++) {
                int v = seg[k];
                int p = atomicAdd(&rcnt[v >> COL_BITS], 1);
                sorted[p] = v & CMASK;
            }
        }
    }
    __syncthreads();
    // coalesced copy to global CSR
    for (int j = t; j < c; j += 256) colsort[gbase + j] = sorted[j];
}

// ---------------- GEMM1: hp[i][j] = dinv[i] * (x[i,:] @ W1[:,j]) ----------------
__global__ __launch_bounds__(256, 2) void k_gemm1(const float* __restrict__ x,
                                                  const float* __restrict__ W1,
                                                  const float* __restrict__ dinv,
                                                  float* __restrict__ hp, int n,
                                                  int total_waves) {
    int lane = threadIdx.x & 63;
    int wid = blockIdx.x * (blockDim.x >> 6) + (threadIdx.x >> 6);

    float w[8][16];
#pragma unroll
    for (int h = 0; h < 2; h++) {
#pragma unroll
        for (int r = 0; r < 4; r++) {
            int k = h * 256 + 4 * lane + r;
            const float4* p = (const float4*)(W1 + k * 16);
            float4 a = p[0], b = p[1], c = p[2], d = p[3];
            float* wr = w[h * 4 + r];
            wr[0] = a.x; wr[1] = a.y; wr[2] = a.z; wr[3] = a.w;
            wr[4] = b.x; wr[5] = b.y; wr[6] = b.z; wr[7] = b.w;
            wr[8] = c.x; wr[9] = c.y; wr[10] = c.z; wr[11] = c.w;
            wr[12] = d.x; wr[13] = d.y; wr[14] = d.z; wr[15] = d.w;
        }
    }

    for (int i0 = wid * 4; i0 < n; i0 += total_waves * 4) {
        float4 xq[8];
        if (i0 + 3 < n) {
            const float4* xp = (const float4*)(x + (size_t)i0 * F0);
#pragma unroll
            for (int q = 0; q < 8; q++) xq[q] = xp[q * 64 + lane];
        } else {
#pragma unroll
            for (int q = 0; q < 8; q++) {
                int r = q >> 1;
                if (i0 + r < n) {
                    const float4* xp = (const float4*)(x + (size_t)(i0 + r) * F0);
                    xq[q] = xp[(q & 1) * 64 + lane];
                } else {
                    xq[q] = make_float4(0.f, 0.f, 0.f, 0.f);
                }
            }
        }
        bool b0 = (lane & 1) != 0;
        bool b1 = (lane & 2) != 0;
        bool b2 = (lane & 4) != 0;
        bool b3 = (lane & 8) != 0;
#pragma unroll
        for (int r = 0; r < 4; r++) {
            float4 xa = xq[2 * r], xb = xq[2 * r + 1];
            float v16[16];
#pragma unroll
            for (int j = 0; j < 16; j++) {
                v16[j] = xa.x * w[0][j] + xa.y * w[1][j] + xa.z * w[2][j] + xa.w * w[3][j]
                       + xb.x * w[4][j] + xb.y * w[5][j] + xb.z * w[6][j] + xb.w * w[7][j];
            }
            float v8[8];
#pragma unroll
            for (int t2 = 0; t2 < 8; t2++) {
                float a = v16[2 * t2], b = v16[2 * t2 + 1];
                float keep = b0 ? b : a;
                float send = b0 ? a : b;
                v8[t2] = keep + __shfl_xor(send, 1);
            }
            float v4[4];
#pragma unroll
            for (int t2 = 0; t2 < 4; t2++) {
                float a = v8[2 * t2], b = v8[2 * t2 + 1];
                float keep = b1 ? b : a;
                float send = b1 ? a : b;
                v4[t2] = keep + __shfl_xor(send, 2);
            }
            float v2[2];
#pragma unroll
            for (int t2 = 0; t2 < 2; t2++) {
                float a = v4[2 * t2], b = v4[2 * t2 + 1];
                float keep = b2 ? b : a;
                float send = b2 ? a : b;
                v2[t2] = keep + __shfl_xor(send, 4);
            }
            float keep = b3 ? v2[1] : v2[0];
            float send = b3 ? v2[0] : v2[1];
            float v1 = keep + __shfl_xor(send, 8);
            v1 += __shfl_xor(v1, 16);
            v1 += __shfl_xor(v1, 32);
            int i = i0 + r;
            if (lane < 16 && i < n)
                hp[(size_t)i * F1 + lane] = dinv[i] * v1;
        }
    }
}

// ---------------- SpMM1 + relu, store s2 = dinv * h1 (16 feats) ----------------
__global__ __launch_bounds__(256) void k_spmm1(const float* __restrict__ hp,
                                               const int* __restrict__ rs,
                                               const int* __restrict__ deg,
                                               const int* __restrict__ colsort,
                                               const float* __restrict__ dinv,
                                               const float* __restrict__ b1,
                                               float* __restrict__ s2, int n) {
    int t = threadIdx.x;
    int lane = t & 63;
    int g = lane >> 4;
    int jf = lane & 15;
    int i = blockIdx.x * 4 + (t >> 6);
    if (i >= n) return;
    int s = rs[i], c = deg[i];
    float acc = (g == 0) ? hp[(size_t)i * F1 + jf] : 0.f;
    int e = g;
    for (; e + 4 < c; e += 8) {
        int c0 = colsort[s + e];
        int c1 = colsort[s + e + 4];
        float v0 = hp[(size_t)c0 * F1 + jf];
        float v1 = hp[(size_t)c1 * F1 + jf];
        acc += v0 + v1;
    }
    if (e < c) acc += hp[(size_t)colsort[s + e] * F1 + jf];
    acc += __shfl_xor(acc, 16);
    acc += __shfl_xor(acc, 32);
    float di = dinv[i];
    float h1 = fmaxf(di * acc + b1[jf], 0.f);
    if (lane < 16) s2[(size_t)i * F1 + jf] = di * h1;
}

// ---------------- SpMM2 (16 feats) + GEMM2 + bias + log_softmax ----------------
__global__ __launch_bounds__(256) void k_spmm2(const float* __restrict__ s2,
                                               const int* __restrict__ rs,
                                               const int* __restrict__ deg,
                                               const int* __restrict__ colsort,
                                               const float* __restrict__ dinv,
                                               const float* __restrict__ W2,
                                               const float* __restrict__ b2,
                                               float* __restrict__ out, int n) {
    __shared__ float sW2[F1 * F2];
    int t = threadIdx.x;
    for (int idx = t; idx < F1 * F2; idx += 256) sW2[idx] = W2[idx];
    __syncthreads();

    int lane = t & 63;
    int g = lane >> 4;
    int jf = lane & 15;
    int i = blockIdx.x * 4 + (t >> 6);
    if (i >= n) return;
    int s = rs[i], c = deg[i];
    float acc = (g == 0) ? s2[(size_t)i * F1 + jf] : 0.f;
    int e = g;
    for (; e + 4 < c; e += 8) {
        int c0 = colsort[s + e];
        int c1 = colsort[s + e + 4];
        float v0 = s2[(size_t)c0 * F1 + jf];
        float v1 = s2[(size_t)c1 * F1 + jf];
        acc += v0 + v1;
    }
    if (e < c) acc += s2[(size_t)colsort[s + e] * F1 + jf];
    acc += __shfl_xor(acc, 16);
    acc += __shfl_xor(acc, 32);
    float z = dinv[i] * acc;

    bool act = lane < F2;
    int k = act ? lane : 0;
    float o = 0.f;
#pragma unroll
    for (int j = 0; j < F1; j++) {
        float zj = __shfl(z, j);
        o += zj * sW2[j * F2 + k];
    }
    float val = act ? o + b2[k] : -INFINITY;
    float m = val;
#pragma unroll
    for (int off = 1; off < 64; off <<= 1) m = fmaxf(m, __shfl_xor(m, off));
    float ex = act ? __expf(val - m) : 0.f;
    float ssum = ex;
#pragma unroll
    for (int off = 1; off < 64; off <<= 1) ssum += __shfl_xor(ssum, off);
    if (act) out[(size_t)i * F2 + lane] = val - m - __logf(ssum);
}

extern "C" void kernel_launch(void* const* d_in, const int* in_sizes, int n_in,
                              void* d_out, int out_size, void* d_ws, size_t ws_size,
                              hipStream_t stream) {
    const float* x  = (const float*)d_in[0];
    const float* W1 = (const float*)d_in[1];
    const float* b1 = (const float*)d_in[2];
    const float* W2 = (const float*)d_in[3];
    const float* b2 = (const float*)d_in[4];
    const int*   ei = (const int*)d_in[5];

    int n = in_sizes[0] / F0;
    int E = in_sizes[5] / 2;
    const int* row = ei;
    const int* col = ei + E;
    int NCB = (n + CB_ROWS - 1) >> CB_SHIFT;   // 391 for n=100000

    // workspace carve-up (4-byte elements)
    int* deg     = (int*)d_ws;                 // n
    int* rs      = deg + n;                    // n
    float* dinv  = (float*)(rs + n);           // n
    int* cnt     = (int*)(dinv + n);           // NCB_MAX*CNT_STRIDE
    int* sbbase  = cnt + NCB_MAX * CNT_STRIDE; // NCB_MAX
    int* colsort = sbbase + NCB_MAX;           // E
    int* ebuf    = colsort + E;                // NCB*CAPCB (~14.4 MB), dead after k_sort
    float* hp    = (float*)ebuf;               // n x 16 (overlay)
    float* s2    = hp + (size_t)n * F1;        // n x 16 (overlay)

    int nchunks = (E + EPB - 1) / EPB;         // 391
    k_zero<<<(NCB * CNT_STRIDE + 255) / 256, 256, 0, stream>>>(cnt, NCB * CNT_STRIDE);
    k_fill<<<nchunks, 512, 0, stream>>>(row, col, E, cnt, ebuf, NCB);
    k_scan2<<<1, NCB_MAX, 0, stream>>>(cnt, NCB, sbbase);
    k_sort<<<NCB, 256, 0, stream>>>(cnt, sbbase, ebuf, n, colsort, deg, rs, dinv);

    int g1_blocks = 2048;
    k_gemm1<<<g1_blocks, 256, 0, stream>>>(x, W1, dinv, hp, n, g1_blocks * 4);
    k_spmm1<<<(n + 3) / 4, 256, 0, stream>>>(hp, rs, deg, colsort, dinv, b1, s2, n);
    k_spmm2<<<(n + 3) / 4, 256, 0, stream>>>(s2, rs, deg, colsort, dinv, W2, b2,
                                             (float*)d_out, n);
}

// Round 4
// 478.382 us; speedup vs baseline: 1.8511x; 1.0479x over previous
//
#include <hip/hip_runtime.h>
#include <hip/hip_fp16.h>
#include <math.h>

#define F0 512
#define F1 16
#define F2 40
#define CB_SHIFT 8          // 256 rows per coarse bucket
#define CB_ROWS 256
#define NCB_MAX 512         // n <= 131072
#define CAPCB 9216          // slots per bucket; mean 8184 at E=3.2M,NCB=391 (+11 sigma)
#define EPB 8192            // edges per fill block
#define COL_BITS 17         // n <= 131072
#define CMASK ((1 << COL_BITS) - 1)
#define CNT_STRIDE 16       // one 64B line per global bucket counter

__global__ void k_zero(int* p, int m) {
    int i = blockIdx.x * blockDim.x + threadIdx.x;
    if (i < m) p[i] = 0;
}

// ---- pass A: per-block counting sort of 8192 edges by coarse bucket; one global
// atomic per (block,bucket); all global stores coalesced runs. No scattered VMEM.
__global__ __launch_bounds__(512) void k_fill(const int* __restrict__ row,
                                              const int* __restrict__ col, int E,
                                              int* cnt, int* __restrict__ ebuf,
                                              int NCB) {
    __shared__ int hcnt[NCB_MAX];   // per-bucket count, then scatter cursor
    __shared__ int lexcl[NCB_MAX];  // block-local exclusive offsets
    __shared__ int hbase[NCB_MAX];  // reserved global base per bucket
    __shared__ int part[NCB_MAX];
    __shared__ int sorted[EPB];
    int t = threadIdx.x;
    int e0 = blockIdx.x * EPB;
    int nloc = min(EPB, E - e0);
    if (t < NCB_MAX) hcnt[t] = 0;
    __syncthreads();

    int rr[16], cc[16];
#pragma unroll
    for (int k = 0; k < 4; k++) {
        int base = t * 4 + k * 2048;
        if (base + 3 < nloc) {
            int4 r4 = *(const int4*)(row + e0 + base);
            int4 c4 = *(const int4*)(col + e0 + base);
            rr[k * 4 + 0] = r4.x; rr[k * 4 + 1] = r4.y;
            rr[k * 4 + 2] = r4.z; rr[k * 4 + 3] = r4.w;
            cc[k * 4 + 0] = c4.x; cc[k * 4 + 1] = c4.y;
            cc[k * 4 + 2] = c4.z; cc[k * 4 + 3] = c4.w;
        } else {
#pragma unroll
            for (int q = 0; q < 4; q++) {
                int e = base + q;
                rr[k * 4 + q] = (e < nloc) ? row[e0 + e] : -1;
                cc[k * 4 + q] = (e < nloc) ? col[e0 + e] : 0;
            }
        }
    }
#pragma unroll
    for (int q = 0; q < 16; q++)
        if (rr[q] >= 0) atomicAdd(&hcnt[rr[q] >> CB_SHIFT], 1);
    __syncthreads();
    int myv = hcnt[t];
    part[t] = myv;
    __syncthreads();
    for (int off = 1; off < NCB_MAX; off <<= 1) {
        int a = (t >= off) ? part[t - off] : 0;
        __syncthreads();
        part[t] += a;
        __syncthreads();
    }
    lexcl[t] = part[t] - myv;
    hbase[t] = (myv > 0) ? atomicAdd(&cnt[t * CNT_STRIDE], myv) : 0;
    hcnt[t] = 0;  // reset as cursor
    __syncthreads();
#pragma unroll
    for (int q = 0; q < 16; q++) {
        int r = rr[q];
        if (r >= 0) {
            int cb = r >> CB_SHIFT;
            int p = lexcl[cb] + atomicAdd(&hcnt[cb], 1);
            sorted[p] = ((r & (CB_ROWS - 1)) << COL_BITS) | cc[q];
        }
    }
    __syncthreads();
    int wv = t >> 6, lane = t & 63;
    for (int cb = wv; cb < NCB; cb += 8) {
        int c = hcnt[cb];
        int ls = lexcl[cb];
        int* dst = ebuf + (size_t)cb * CAPCB + hbase[cb];
        for (int j = lane; j < c; j += 64) dst[j] = sorted[ls + j];
    }
}

// ---- pass B: exclusive scan of bucket totals -> global CSR bases ----
__global__ __launch_bounds__(512) void k_scan2(const int* __restrict__ cnt, int NCB,
                                               int* __restrict__ sbbase) {
    __shared__ int part[NCB_MAX];
    int t = threadIdx.x;
    int v = (t < NCB) ? cnt[t * CNT_STRIDE] : 0;
    part[t] = v;
    __syncthreads();
    for (int off = 1; off < NCB_MAX; off <<= 1) {
        int a = (t >= off) ? part[t - off] : 0;
        __syncthreads();
        part[t] += a;
        __syncthreads();
    }
    if (t < NCB) sbbase[t] = part[t] - v;
}

// ---- pass C: per-bucket counting sort fully in LDS; coalesced colsort writes ----
__global__ __launch_bounds__(256) void k_sort(const int* __restrict__ cnt,
                                              const int* __restrict__ sbbase,
                                              const int* __restrict__ ebuf, int n,
                                              int* __restrict__ colsort,
                                              int* __restrict__ deg,
                                              int* __restrict__ rs,
                                              float* __restrict__ dinv) {
    __shared__ int rcnt[CB_ROWS];
    __shared__ int rexcl[CB_ROWS];
    __shared__ int sorted[CAPCB];
    int cb = blockIdx.x;
    int t = threadIdx.x;
    int c = cnt[cb * CNT_STRIDE];
    const int* seg = ebuf + (size_t)cb * CAPCB;
    rcnt[t] = 0;
    __syncthreads();
    for (int base = t * 4; base < c; base += 1024) {
        if (base + 3 < c) {
            int4 v = *(const int4*)(seg + base);
            atomicAdd(&rcnt[v.x >> COL_BITS], 1);
            atomicAdd(&rcnt[v.y >> COL_BITS], 1);
            atomicAdd(&rcnt[v.z >> COL_BITS], 1);
            atomicAdd(&rcnt[v.w >> COL_BITS], 1);
        } else {
            for (int k = base; k < c; k++) atomicAdd(&rcnt[seg[k] >> COL_BITS], 1);
        }
    }
    __syncthreads();
    int myc = rcnt[t];
    rexcl[t] = myc;
    __syncthreads();
    for (int off = 1; off < CB_ROWS; off <<= 1) {
        int a = (t >= off) ? rexcl[t - off] : 0;
        __syncthreads();
        rexcl[t] += a;
        __syncthreads();
    }
    int excl = rexcl[t] - myc;
    int gbase = sbbase[cb];
    int i = (cb << CB_SHIFT) + t;
    if (i < n) {
        deg[i] = myc;
        rs[i] = gbase + excl;
        dinv[i] = rsqrtf((float)(myc + 1));
    }
    rcnt[t] = excl;  // reuse as cursor
    __syncthreads();
    for (int base = t * 4; base < c; base += 1024) {
        if (base + 3 < c) {
            int4 v = *(const int4*)(seg + base);
            int p0 = atomicAdd(&rcnt[v.x >> COL_BITS], 1); sorted[p0] = v.x & CMASK;
            int p1 = atomicAdd(&rcnt[v.y >> COL_BITS], 1); sorted[p1] = v.y & CMASK;
            int p2 = atomicAdd(&rcnt[v.z >> COL_BITS], 1); sorted[p2] = v.z & CMASK;
            int p3 = atomicAdd(&rcnt[v.w >> COL_BITS], 1); sorted[p3] = v.w & CMASK;
        } else {
            for (int k = base; k < c; k++) {
                int v = seg[k];
                int p = atomicAdd(&rcnt[v >> COL_BITS], 1);
                sorted[p] = v & CMASK;
            }
        }
    }
    __syncthreads();
    for (int j = t; j < c; j += 256) colsort[gbase + j] = sorted[j];
}

// ---------------- GEMM1: hp[i][j] = fp16( dinv[i] * (x[i,:] @ W1[:,j]) ) --------
__global__ __launch_bounds__(256, 2) void k_gemm1(const float* __restrict__ x,
                                                  const float* __restrict__ W1,
                                                  const float* __restrict__ dinv,
                                                  __half* __restrict__ hp, int n,
                                                  int total_waves) {
    int lane = threadIdx.x & 63;
    int wid = blockIdx.x * (blockDim.x >> 6) + (threadIdx.x >> 6);

    float w[8][16];
#pragma unroll
    for (int h = 0; h < 2; h++) {
#pragma unroll
        for (int r = 0; r < 4; r++) {
            int k = h * 256 + 4 * lane + r;
            const float4* p = (const float4*)(W1 + k * 16);
            float4 a = p[0], b = p[1], c = p[2], d = p[3];
            float* wr = w[h * 4 + r];
            wr[0] = a.x; wr[1] = a.y; wr[2] = a.z; wr[3] = a.w;
            wr[4] = b.x; wr[5] = b.y; wr[6] = b.z; wr[7] = b.w;
            wr[8] = c.x; wr[9] = c.y; wr[10] = c.z; wr[11] = c.w;
            wr[12] = d.x; wr[13] = d.y; wr[14] = d.z; wr[15] = d.w;
        }
    }

    for (int i0 = wid * 4; i0 < n; i0 += total_waves * 4) {
        float4 xq[8];
        if (i0 + 3 < n) {
            const float4* xp = (const float4*)(x + (size_t)i0 * F0);
#pragma unroll
            for (int q = 0; q < 8; q++) xq[q] = xp[q * 64 + lane];
        } else {
#pragma unroll
            for (int q = 0; q < 8; q++) {
                int r = q >> 1;
                if (i0 + r < n) {
                    const float4* xp = (const float4*)(x + (size_t)(i0 + r) * F0);
                    xq[q] = xp[(q & 1) * 64 + lane];
                } else {
                    xq[q] = make_float4(0.f, 0.f, 0.f, 0.f);
                }
            }
        }
        bool b0 = (lane & 1) != 0;
        bool b1 = (lane & 2) != 0;
        bool b2 = (lane & 4) != 0;
        bool b3 = (lane & 8) != 0;
#pragma unroll
        for (int r = 0; r < 4; r++) {
            float4 xa = xq[2 * r], xb = xq[2 * r + 1];
            float v16[16];
#pragma unroll
            for (int j = 0; j < 16; j++) {
                v16[j] = xa.x * w[0][j] + xa.y * w[1][j] + xa.z * w[2][j] + xa.w * w[3][j]
                       + xb.x * w[4][j] + xb.y * w[5][j] + xb.z * w[6][j] + xb.w * w[7][j];
            }
            float v8[8];
#pragma unroll
            for (int t2 = 0; t2 < 8; t2++) {
                float a = v16[2 * t2], b = v16[2 * t2 + 1];
                float keep = b0 ? b : a;
                float send = b0 ? a : b;
                v8[t2] = keep + __shfl_xor(send, 1);
            }
            float v4[4];
#pragma unroll
            for (int t2 = 0; t2 < 4; t2++) {
                float a = v8[2 * t2], b = v8[2 * t2 + 1];
                float keep = b1 ? b : a;
                float send = b1 ? a : b;
                v4[t2] = keep + __shfl_xor(send, 2);
            }
            float v2[2];
#pragma unroll
            for (int t2 = 0; t2 < 2; t2++) {
                float a = v4[2 * t2], b = v4[2 * t2 + 1];
                float keep = b2 ? b : a;
                float send = b2 ? a : b;
                v2[t2] = keep + __shfl_xor(send, 4);
            }
            float keep = b3 ? v2[1] : v2[0];
            float send = b3 ? v2[0] : v2[1];
            float v1 = keep + __shfl_xor(send, 8);
            v1 += __shfl_xor(v1, 16);
            v1 += __shfl_xor(v1, 32);
            int i = i0 + r;
            if (lane < 16 && i < n)
                hp[(size_t)i * F1 + lane] = __float2half_rn(dinv[i] * v1);
        }
    }
}

// ---------------- SpMM1 + relu, store s2 = fp16(dinv * h1) (16 feats) ----------
// Table hp is 3.2 MB fp16 -> fully L2-resident per XCD; gathers are L2 hits.
__global__ __launch_bounds__(256) void k_spmm1(const __half* __restrict__ hp,
                                               const int* __restrict__ rs,
                                               const int* __restrict__ deg,
                                               const int* __restrict__ colsort,
                                               const float* __restrict__ dinv,
                                               const float* __restrict__ b1,
                                               __half* __restrict__ s2, int n) {
    int t = threadIdx.x;
    int lane = t & 63;
    int g = lane >> 4;
    int jf = lane & 15;
    int i = blockIdx.x * 4 + (t >> 6);
    if (i >= n) return;
    int s = rs[i], c = deg[i];
    float acc = (g == 0) ? __half2float(hp[(size_t)i * F1 + jf]) : 0.f;
    int e = g;
    for (; e + 12 < c; e += 16) {
        int c0 = colsort[s + e];
        int c1 = colsort[s + e + 4];
        int c2 = colsort[s + e + 8];
        int c3 = colsort[s + e + 12];
        float v0 = __half2float(hp[(size_t)c0 * F1 + jf]);
        float v1 = __half2float(hp[(size_t)c1 * F1 + jf]);
        float v2 = __half2float(hp[(size_t)c2 * F1 + jf]);
        float v3 = __half2float(hp[(size_t)c3 * F1 + jf]);
        acc += (v0 + v1) + (v2 + v3);
    }
    for (; e < c; e += 4)
        acc += __half2float(hp[(size_t)colsort[s + e] * F1 + jf]);
    acc += __shfl_xor(acc, 16);
    acc += __shfl_xor(acc, 32);
    float di = dinv[i];
    float h1 = fmaxf(di * acc + b1[jf], 0.f);
    if (lane < 16) s2[(size_t)i * F1 + jf] = __float2half_rn(di * h1);
}

// ---------------- SpMM2 (16 feats) + GEMM2 + bias + log_softmax ----------------
__global__ __launch_bounds__(256) void k_spmm2(const __half* __restrict__ s2,
                                               const int* __restrict__ rs,
                                               const int* __restrict__ deg,
                                               const int* __restrict__ colsort,
                                               const float* __restrict__ dinv,
                                               const float* __restrict__ W2,
                                               const float* __restrict__ b2,
                                               float* __restrict__ out, int n) {
    __shared__ float sW2[F1 * F2];
    int t = threadIdx.x;
    for (int idx = t; idx < F1 * F2; idx += 256) sW2[idx] = W2[idx];
    __syncthreads();

    int lane = t & 63;
    int g = lane >> 4;
    int jf = lane & 15;
    int i = blockIdx.x * 4 + (t >> 6);
    if (i >= n) return;
    int s = rs[i], c = deg[i];
    float acc = (g == 0) ? __half2float(s2[(size_t)i * F1 + jf]) : 0.f;
    int e = g;
    for (; e + 12 < c; e += 16) {
        int c0 = colsort[s + e];
        int c1 = colsort[s + e + 4];
        int c2 = colsort[s + e + 8];
        int c3 = colsort[s + e + 12];
        float v0 = __half2float(s2[(size_t)c0 * F1 + jf]);
        float v1 = __half2float(s2[(size_t)c1 * F1 + jf]);
        float v2 = __half2float(s2[(size_t)c2 * F1 + jf]);
        float v3 = __half2float(s2[(size_t)c3 * F1 + jf]);
        acc += (v0 + v1) + (v2 + v3);
    }
    for (; e < c; e += 4)
        acc += __half2float(s2[(size_t)colsort[s + e] * F1 + jf]);
    acc += __shfl_xor(acc, 16);
    acc += __shfl_xor(acc, 32);
    float z = dinv[i] * acc;

    bool act = lane < F2;
    int k = act ? lane : 0;
    float o = 0.f;
#pragma unroll
    for (int j = 0; j < F1; j++) {
        float zj = __shfl(z, j);
        o += zj * sW2[j * F2 + k];
    }
    float val = act ? o + b2[k] : -INFINITY;
    float m = val;
#pragma unroll
    for (int off = 1; off < 64; off <<= 1) m = fmaxf(m, __shfl_xor(m, off));
    float ex = act ? __expf(val - m) : 0.f;
    float ssum = ex;
#pragma unroll
    for (int off = 1; off < 64; off <<= 1) ssum += __shfl_xor(ssum, off);
    if (act) out[(size_t)i * F2 + lane] = val - m - __logf(ssum);
}

extern "C" void kernel_launch(void* const* d_in, const int* in_sizes, int n_in,
                              void* d_out, int out_size, void* d_ws, size_t ws_size,
                              hipStream_t stream) {
    const float* x  = (const float*)d_in[0];
    const float* W1 = (const float*)d_in[1];
    const float* b1 = (const float*)d_in[2];
    const float* W2 = (const float*)d_in[3];
    const float* b2 = (const float*)d_in[4];
    const int*   ei = (const int*)d_in[5];

    int n = in_sizes[0] / F0;
    int E = in_sizes[5] / 2;
    const int* row = ei;
    const int* col = ei + E;
    int NCB = (n + CB_ROWS - 1) >> CB_SHIFT;   // 391 for n=100000

    // workspace carve-up (4-byte elements)
    int* deg     = (int*)d_ws;                 // n
    int* rs      = deg + n;                    // n
    float* dinv  = (float*)(rs + n);           // n
    int* cnt     = (int*)(dinv + n);           // NCB_MAX*CNT_STRIDE
    int* sbbase  = cnt + NCB_MAX * CNT_STRIDE; // NCB_MAX
    int* colsort = sbbase + NCB_MAX;           // E
    int* ebuf    = colsort + E;                // NCB*CAPCB (~14.4 MB), dead after k_sort
    __half* hp   = (__half*)ebuf;              // n x 16 fp16 (overlay, 3.2 MB)
    __half* s2   = hp + (size_t)n * F1;        // n x 16 fp16 (overlay, 3.2 MB)

    int nchunks = (E + EPB - 1) / EPB;         // 391
    k_zero<<<(NCB * CNT_STRIDE + 255) / 256, 256, 0, stream>>>(cnt, NCB * CNT_STRIDE);
    k_fill<<<nchunks, 512, 0, stream>>>(row, col, E, cnt, ebuf, NCB);
    k_scan2<<<1, NCB_MAX, 0, stream>>>(cnt, NCB, sbbase);
    k_sort<<<NCB, 256, 0, stream>>>(cnt, sbbase, ebuf, n, colsort, deg, rs, dinv);

    int g1_blocks = 2048;
    k_gemm1<<<g1_blocks, 256, 0, stream>>>(x, W1, dinv, hp, n, g1_blocks * 4);
    k_spmm1<<<(n + 3) / 4, 256, 0, stream>>>(hp, rs, deg, colsort, dinv, b1, s2, n);
    k_spmm2<<<(n + 3) / 4, 256, 0, stream>>>(s2, rs, deg, colsort, dinv, W2, b2,
                                             (float*)d_out, n);
}

// Round 5
// 429.748 us; speedup vs baseline: 2.0606x; 1.1132x over previous
//
#include <hip/hip_runtime.h>
#include <hip/hip_fp16.h>
#include <math.h>

#define F0 512
#define F1 16
#define F2 40
#define CB_SHIFT 8          // 256 rows per coarse bucket
#define CB_ROWS 256
#define NCB_MAX 512         // n <= 131072
#define CAPCB 9216          // slots per bucket; mean 8184 at E=3.2M,NCB=391 (+11 sigma)
#define EPB 8192            // edges per fill block
#define COL_BITS 17         // n <= 131072
#define CMASK ((1 << COL_BITS) - 1)
#define CNT_STRIDE 16       // one 64B line per global bucket counter

__global__ void k_zero(int* p, int m) {
    int i = blockIdx.x * blockDim.x + threadIdx.x;
    if (i < m) p[i] = 0;
}

// ---- pass A: per-block counting sort of 8192 edges by coarse bucket; one global
// atomic per (block,bucket); all global stores coalesced runs. No scattered VMEM.
__global__ __launch_bounds__(512) void k_fill(const int* __restrict__ row,
                                              const int* __restrict__ col, int E,
                                              int* cnt, int* __restrict__ ebuf,
                                              int NCB) {
    __shared__ int hcnt[NCB_MAX];   // per-bucket count, then scatter cursor
    __shared__ int lexcl[NCB_MAX];  // block-local exclusive offsets
    __shared__ int hbase[NCB_MAX];  // reserved global base per bucket
    __shared__ int part[NCB_MAX];
    __shared__ int sorted[EPB];
    int t = threadIdx.x;
    int e0 = blockIdx.x * EPB;
    int nloc = min(EPB, E - e0);
    if (t < NCB_MAX) hcnt[t] = 0;
    __syncthreads();

    int rr[16], cc[16];
#pragma unroll
    for (int k = 0; k < 4; k++) {
        int base = t * 4 + k * 2048;
        if (base + 3 < nloc) {
            int4 r4 = *(const int4*)(row + e0 + base);
            int4 c4 = *(const int4*)(col + e0 + base);
            rr[k * 4 + 0] = r4.x; rr[k * 4 + 1] = r4.y;
            rr[k * 4 + 2] = r4.z; rr[k * 4 + 3] = r4.w;
            cc[k * 4 + 0] = c4.x; cc[k * 4 + 1] = c4.y;
            cc[k * 4 + 2] = c4.z; cc[k * 4 + 3] = c4.w;
        } else {
#pragma unroll
            for (int q = 0; q < 4; q++) {
                int e = base + q;
                rr[k * 4 + q] = (e < nloc) ? row[e0 + e] : -1;
                cc[k * 4 + q] = (e < nloc) ? col[e0 + e] : 0;
            }
        }
    }
#pragma unroll
    for (int q = 0; q < 16; q++)
        if (rr[q] >= 0) atomicAdd(&hcnt[rr[q] >> CB_SHIFT], 1);
    __syncthreads();
    int myv = hcnt[t];
    part[t] = myv;
    __syncthreads();
    for (int off = 1; off < NCB_MAX; off <<= 1) {
        int a = (t >= off) ? part[t - off] : 0;
        __syncthreads();
        part[t] += a;
        __syncthreads();
    }
    lexcl[t] = part[t] - myv;
    hbase[t] = (myv > 0) ? atomicAdd(&cnt[t * CNT_STRIDE], myv) : 0;
    hcnt[t] = 0;  // reset as cursor
    __syncthreads();
#pragma unroll
    for (int q = 0; q < 16; q++) {
        int r = rr[q];
        if (r >= 0) {
            int cb = r >> CB_SHIFT;
            int p = lexcl[cb] + atomicAdd(&hcnt[cb], 1);
            sorted[p] = ((r & (CB_ROWS - 1)) << COL_BITS) | cc[q];
        }
    }
    __syncthreads();
    int wv = t >> 6, lane = t & 63;
    for (int cb = wv; cb < NCB; cb += 8) {
        int c = hcnt[cb];
        int ls = lexcl[cb];
        int* dst = ebuf + (size_t)cb * CAPCB + hbase[cb];
        for (int j = lane; j < c; j += 64) dst[j] = sorted[ls + j];
    }
}

// ---- pass B: exclusive scan of bucket totals -> global CSR bases ----
__global__ __launch_bounds__(512) void k_scan2(const int* __restrict__ cnt, int NCB,
                                               int* __restrict__ sbbase) {
    __shared__ int part[NCB_MAX];
    int t = threadIdx.x;
    int v = (t < NCB) ? cnt[t * CNT_STRIDE] : 0;
    part[t] = v;
    __syncthreads();
    for (int off = 1; off < NCB_MAX; off <<= 1) {
        int a = (t >= off) ? part[t - off] : 0;
        __syncthreads();
        part[t] += a;
        __syncthreads();
    }
    if (t < NCB) sbbase[t] = part[t] - v;
}

// ---- pass C: per-bucket counting sort fully in LDS; coalesced colsort writes ----
__global__ __launch_bounds__(256) void k_sort(const int* __restrict__ cnt,
                                              const int* __restrict__ sbbase,
                                              const int* __restrict__ ebuf, int n,
                                              int* __restrict__ colsort,
                                              int* __restrict__ deg,
                                              int* __restrict__ rs,
                                              float* __restrict__ dinv) {
    __shared__ int rcnt[CB_ROWS];
    __shared__ int rexcl[CB_ROWS];
    __shared__ int sorted[CAPCB];
    int cb = blockIdx.x;
    int t = threadIdx.x;
    int c = cnt[cb * CNT_STRIDE];
    const int* seg = ebuf + (size_t)cb * CAPCB;
    rcnt[t] = 0;
    __syncthreads();
    for (int base = t * 4; base < c; base += 1024) {
        if (base + 3 < c) {
            int4 v = *(const int4*)(seg + base);
            atomicAdd(&rcnt[v.x >> COL_BITS], 1);
            atomicAdd(&rcnt[v.y >> COL_BITS], 1);
            atomicAdd(&rcnt[v.z >> COL_BITS], 1);
            atomicAdd(&rcnt[v.w >> COL_BITS], 1);
        } else {
            for (int k = base; k < c; k++) atomicAdd(&rcnt[seg[k] >> COL_BITS], 1);
        }
    }
    __syncthreads();
    int myc = rcnt[t];
    rexcl[t] = myc;
    __syncthreads();
    for (int off = 1; off < CB_ROWS; off <<= 1) {
        int a = (t >= off) ? rexcl[t - off] : 0;
        __syncthreads();
        rexcl[t] += a;
        __syncthreads();
    }
    int excl = rexcl[t] - myc;
    int gbase = sbbase[cb];
    int i = (cb << CB_SHIFT) + t;
    if (i < n) {
        deg[i] = myc;
        rs[i] = gbase + excl;
        dinv[i] = rsqrtf((float)(myc + 1));
    }
    rcnt[t] = excl;  // reuse as cursor
    __syncthreads();
    for (int base = t * 4; base < c; base += 1024) {
        if (base + 3 < c) {
            int4 v = *(const int4*)(seg + base);
            int p0 = atomicAdd(&rcnt[v.x >> COL_BITS], 1); sorted[p0] = v.x & CMASK;
            int p1 = atomicAdd(&rcnt[v.y >> COL_BITS], 1); sorted[p1] = v.y & CMASK;
            int p2 = atomicAdd(&rcnt[v.z >> COL_BITS], 1); sorted[p2] = v.z & CMASK;
            int p3 = atomicAdd(&rcnt[v.w >> COL_BITS], 1); sorted[p3] = v.w & CMASK;
        } else {
            for (int k = base; k < c; k++) {
                int v = seg[k];
                int p = atomicAdd(&rcnt[v >> COL_BITS], 1);
                sorted[p] = v & CMASK;
            }
        }
    }
    __syncthreads();
    for (int j = t; j < c; j += 256) colsort[gbase + j] = sorted[j];
}

// ---------------- GEMM1: hp[i][j] = fp16( dinv[i] * (x[i,:] @ W1[:,j]) ) --------
__global__ __launch_bounds__(256, 2) void k_gemm1(const float* __restrict__ x,
                                                  const float* __restrict__ W1,
                                                  const float* __restrict__ dinv,
                                                  __half* __restrict__ hp, int n,
                                                  int total_waves) {
    int lane = threadIdx.x & 63;
    int wid = blockIdx.x * (blockDim.x >> 6) + (threadIdx.x >> 6);

    float w[8][16];
#pragma unroll
    for (int h = 0; h < 2; h++) {
#pragma unroll
        for (int r = 0; r < 4; r++) {
            int k = h * 256 + 4 * lane + r;
            const float4* p = (const float4*)(W1 + k * 16);
            float4 a = p[0], b = p[1], c = p[2], d = p[3];
            float* wr = w[h * 4 + r];
            wr[0] = a.x; wr[1] = a.y; wr[2] = a.z; wr[3] = a.w;
            wr[4] = b.x; wr[5] = b.y; wr[6] = b.z; wr[7] = b.w;
            wr[8] = c.x; wr[9] = c.y; wr[10] = c.z; wr[11] = c.w;
            wr[12] = d.x; wr[13] = d.y; wr[14] = d.z; wr[15] = d.w;
        }
    }

    for (int i0 = wid * 4; i0 < n; i0 += total_waves * 4) {
        float4 xq[8];
        if (i0 + 3 < n) {
            const float4* xp = (const float4*)(x + (size_t)i0 * F0);
#pragma unroll
            for (int q = 0; q < 8; q++) xq[q] = xp[q * 64 + lane];
        } else {
#pragma unroll
            for (int q = 0; q < 8; q++) {
                int r = q >> 1;
                if (i0 + r < n) {
                    const float4* xp = (const float4*)(x + (size_t)(i0 + r) * F0);
                    xq[q] = xp[(q & 1) * 64 + lane];
                } else {
                    xq[q] = make_float4(0.f, 0.f, 0.f, 0.f);
                }
            }
        }
        bool b0 = (lane & 1) != 0;
        bool b1 = (lane & 2) != 0;
        bool b2 = (lane & 4) != 0;
        bool b3 = (lane & 8) != 0;
#pragma unroll
        for (int r = 0; r < 4; r++) {
            float4 xa = xq[2 * r], xb = xq[2 * r + 1];
            float v16[16];
#pragma unroll
            for (int j = 0; j < 16; j++) {
                v16[j] = xa.x * w[0][j] + xa.y * w[1][j] + xa.z * w[2][j] + xa.w * w[3][j]
                       + xb.x * w[4][j] + xb.y * w[5][j] + xb.z * w[6][j] + xb.w * w[7][j];
            }
            float v8[8];
#pragma unroll
            for (int t2 = 0; t2 < 8; t2++) {
                float a = v16[2 * t2], b = v16[2 * t2 + 1];
                float keep = b0 ? b : a;
                float send = b0 ? a : b;
                v8[t2] = keep + __shfl_xor(send, 1);
            }
            float v4[4];
#pragma unroll
            for (int t2 = 0; t2 < 4; t2++) {
                float a = v8[2 * t2], b = v8[2 * t2 + 1];
                float keep = b1 ? b : a;
                float send = b1 ? a : b;
                v4[t2] = keep + __shfl_xor(send, 2);
            }
            float v2[2];
#pragma unroll
            for (int t2 = 0; t2 < 2; t2++) {
                float a = v4[2 * t2], b = v4[2 * t2 + 1];
                float keep = b2 ? b : a;
                float send = b2 ? a : b;
                v2[t2] = keep + __shfl_xor(send, 4);
            }
            float keep = b3 ? v2[1] : v2[0];
            float send = b3 ? v2[0] : v2[1];
            float v1 = keep + __shfl_xor(send, 8);
            v1 += __shfl_xor(v1, 16);
            v1 += __shfl_xor(v1, 32);
            int i = i0 + r;
            if (lane < 16 && i < n)
                hp[(size_t)i * F1 + lane] = __float2half_rn(dinv[i] * v1);
        }
    }
}

// ---------------- SpMM1 + relu, store s2 = fp16(dinv * h1) (16 feats) ----------
// One row per 16-lane group (16 rows/block): 32 gathers in flight per wave.
__global__ __launch_bounds__(256) void k_spmm1(const __half* __restrict__ hp,
                                               const int* __restrict__ rs,
                                               const int* __restrict__ deg,
                                               const int* __restrict__ colsort,
                                               const float* __restrict__ dinv,
                                               const float* __restrict__ b1,
                                               __half* __restrict__ s2, int n) {
    int t = threadIdx.x;
    int jf = t & 15;
    int i = blockIdx.x * 16 + (t >> 4);
    if (i >= n) return;
    int s = rs[i], c = deg[i];
    const int* cs = colsort + s;
    float acc = __half2float(hp[(size_t)i * F1 + jf]);  // self loop
    int e = 0;
    for (; e + 7 < c; e += 8) {
        int c0 = cs[e];     int c1 = cs[e + 1];
        int c2 = cs[e + 2]; int c3 = cs[e + 3];
        int c4 = cs[e + 4]; int c5 = cs[e + 5];
        int c6 = cs[e + 6]; int c7 = cs[e + 7];
        float v0 = __half2float(hp[(size_t)c0 * F1 + jf]);
        float v1 = __half2float(hp[(size_t)c1 * F1 + jf]);
        float v2 = __half2float(hp[(size_t)c2 * F1 + jf]);
        float v3 = __half2float(hp[(size_t)c3 * F1 + jf]);
        float v4 = __half2float(hp[(size_t)c4 * F1 + jf]);
        float v5 = __half2float(hp[(size_t)c5 * F1 + jf]);
        float v6 = __half2float(hp[(size_t)c6 * F1 + jf]);
        float v7 = __half2float(hp[(size_t)c7 * F1 + jf]);
        acc += ((v0 + v1) + (v2 + v3)) + ((v4 + v5) + (v6 + v7));
    }
    for (; e + 3 < c; e += 4) {
        int c0 = cs[e];     int c1 = cs[e + 1];
        int c2 = cs[e + 2]; int c3 = cs[e + 3];
        float v0 = __half2float(hp[(size_t)c0 * F1 + jf]);
        float v1 = __half2float(hp[(size_t)c1 * F1 + jf]);
        float v2 = __half2float(hp[(size_t)c2 * F1 + jf]);
        float v3 = __half2float(hp[(size_t)c3 * F1 + jf]);
        acc += (v0 + v1) + (v2 + v3);
    }
    for (; e < c; e++)
        acc += __half2float(hp[(size_t)cs[e] * F1 + jf]);
    float di = dinv[i];
    float h1 = fmaxf(di * acc + b1[jf], 0.f);
    s2[(size_t)i * F1 + jf] = __float2half_rn(di * h1);
}

// ---------------- SpMM2 (16 feats) + GEMM2 + bias + log_softmax ----------------
// One row per 16-lane group; epilogue group-local: lane jf owns out cols
// {jf, jf+16, jf+32(<40)}; softmax via width-16 butterflies.
__global__ __launch_bounds__(256) void k_spmm2(const __half* __restrict__ s2,
                                               const int* __restrict__ rs,
                                               const int* __restrict__ deg,
                                               const int* __restrict__ colsort,
                                               const float* __restrict__ dinv,
                                               const float* __restrict__ W2,
                                               const float* __restrict__ b2,
                                               float* __restrict__ out, int n) {
    __shared__ float sW2[F1 * F2];
    int t = threadIdx.x;
    for (int idx = t; idx < F1 * F2; idx += 256) sW2[idx] = W2[idx];
    __syncthreads();

    int jf = t & 15;
    int i = blockIdx.x * 16 + (t >> 4);
    if (i >= n) return;
    int s = rs[i], c = deg[i];
    const int* cs = colsort + s;
    float acc = __half2float(s2[(size_t)i * F1 + jf]);  // self loop
    int e = 0;
    for (; e + 7 < c; e += 8) {
        int c0 = cs[e];     int c1 = cs[e + 1];
        int c2 = cs[e + 2]; int c3 = cs[e + 3];
        int c4 = cs[e + 4]; int c5 = cs[e + 5];
        int c6 = cs[e + 6]; int c7 = cs[e + 7];
        float v0 = __half2float(s2[(size_t)c0 * F1 + jf]);
        float v1 = __half2float(s2[(size_t)c1 * F1 + jf]);
        float v2 = __half2float(s2[(size_t)c2 * F1 + jf]);
        float v3 = __half2float(s2[(size_t)c3 * F1 + jf]);
        float v4 = __half2float(s2[(size_t)c4 * F1 + jf]);
        float v5 = __half2float(s2[(size_t)c5 * F1 + jf]);
        float v6 = __half2float(s2[(size_t)c6 * F1 + jf]);
        float v7 = __half2float(s2[(size_t)c7 * F1 + jf]);
        acc += ((v0 + v1) + (v2 + v3)) + ((v4 + v5) + (v6 + v7));
    }
    for (; e + 3 < c; e += 4) {
        int c0 = cs[e];     int c1 = cs[e + 1];
        int c2 = cs[e + 2]; int c3 = cs[e + 3];
        float v0 = __half2float(s2[(size_t)c0 * F1 + jf]);
        float v1 = __half2float(s2[(size_t)c1 * F1 + jf]);
        float v2 = __half2float(s2[(size_t)c2 * F1 + jf]);
        float v3 = __half2float(s2[(size_t)c3 * F1 + jf]);
        acc += (v0 + v1) + (v2 + v3);
    }
    for (; e < c; e++)
        acc += __half2float(s2[(size_t)cs[e] * F1 + jf]);
    float z = dinv[i] * acc;

    // GEMM2: lane jf computes cols k0=jf, k1=jf+16, k2=jf+32 (if <40)
    int k0 = jf, k1 = jf + 16, k2 = jf + 32;
    bool has2 = (k2 < F2);
    float o0 = 0.f, o1 = 0.f, o2 = 0.f;
#pragma unroll
    for (int j = 0; j < F1; j++) {
        float zj = __shfl(z, j, 16);
        o0 += zj * sW2[j * F2 + k0];
        o1 += zj * sW2[j * F2 + k1];
        o2 += zj * sW2[j * F2 + k2 - (has2 ? 0 : 32)];  // dummy safe index if !has2
    }
    float v0 = o0 + b2[k0];
    float v1 = o1 + b2[k1];
    float v2 = has2 ? (o2 + b2[k2]) : -INFINITY;
    float m = fmaxf(fmaxf(v0, v1), v2);
#pragma unroll
    for (int off = 1; off < 16; off <<= 1) m = fmaxf(m, __shfl_xor(m, off, 16));
    float ssum = __expf(v0 - m) + __expf(v1 - m) + (has2 ? __expf(v2 - m) : 0.f);
#pragma unroll
    for (int off = 1; off < 16; off <<= 1) ssum += __shfl_xor(ssum, off, 16);
    float lse = m + __logf(ssum);
    float* orow = out + (size_t)i * F2;
    orow[k0] = v0 - lse;
    orow[k1] = v1 - lse;
    if (has2) orow[k2] = v2 - lse;
}

extern "C" void kernel_launch(void* const* d_in, const int* in_sizes, int n_in,
                              void* d_out, int out_size, void* d_ws, size_t ws_size,
                              hipStream_t stream) {
    const float* x  = (const float*)d_in[0];
    const float* W1 = (const float*)d_in[1];
    const float* b1 = (const float*)d_in[2];
    const float* W2 = (const float*)d_in[3];
    const float* b2 = (const float*)d_in[4];
    const int*   ei = (const int*)d_in[5];

    int n = in_sizes[0] / F0;
    int E = in_sizes[5] / 2;
    const int* row = ei;
    const int* col = ei + E;
    int NCB = (n + CB_ROWS - 1) >> CB_SHIFT;   // 391 for n=100000

    // workspace carve-up (4-byte elements)
    int* deg     = (int*)d_ws;                 // n
    int* rs      = deg + n;                    // n
    float* dinv  = (float*)(rs + n);           // n
    int* cnt     = (int*)(dinv + n);           // NCB_MAX*CNT_STRIDE
    int* sbbase  = cnt + NCB_MAX * CNT_STRIDE; // NCB_MAX
    int* colsort = sbbase + NCB_MAX;           // E
    int* ebuf    = colsort + E;                // NCB*CAPCB (~14.4 MB), dead after k_sort
    __half* hp   = (__half*)ebuf;              // n x 16 fp16 (overlay, 3.2 MB)
    __half* s2   = hp + (size_t)n * F1;        // n x 16 fp16 (overlay, 3.2 MB)

    int nchunks = (E + EPB - 1) / EPB;         // 391
    k_zero<<<(NCB * CNT_STRIDE + 255) / 256, 256, 0, stream>>>(cnt, NCB * CNT_STRIDE);
    k_fill<<<nchunks, 512, 0, stream>>>(row, col, E, cnt, ebuf, NCB);
    k_scan2<<<1, NCB_MAX, 0, stream>>>(cnt, NCB, sbbase);
    k_sort<<<NCB, 256, 0, stream>>>(cnt, sbbase, ebuf, n, colsort, deg, rs, dinv);

    int g1_blocks = 2048;
    k_gemm1<<<g1_blocks, 256, 0, stream>>>(x, W1, dinv, hp, n, g1_blocks * 4);
    k_spmm1<<<(n + 15) / 16, 256, 0, stream>>>(hp, rs, deg, colsort, dinv, b1, s2, n);
    k_spmm2<<<(n + 15) / 16, 256, 0, stream>>>(s2, rs, deg, colsort, dinv, W2, b2,
                                               (float*)d_out, n);
}

// Round 6
// 423.662 us; speedup vs baseline: 2.0902x; 1.0144x over previous
//
#include <hip/hip_runtime.h>
#include <hip/hip_fp16.h>
#include <math.h>

#define F0 512
#define F1 16
#define F2 40
#define CB_SHIFT 8          // 256 rows per coarse bucket
#define CB_ROWS 256
#define NCB_MAX 512         // n <= 131072
#define CAPCB 9216          // slots per bucket; mean 8184 at E=3.2M,NCB=391 (+11 sigma)
#define EPB 8192            // edges per fill block
#define COL_BITS 17         // n <= 131072
#define CMASK ((1 << COL_BITS) - 1)
#define CNT_STRIDE 16       // one 64B line per global bucket counter

__global__ void k_zero(int* p, int m) {
    int i = blockIdx.x * blockDim.x + threadIdx.x;
    if (i < m) p[i] = 0;
}

// ---- pass A: per-block counting sort of 8192 edges by coarse bucket; one global
// atomic per (block,bucket); all global stores coalesced runs. No scattered VMEM.
__global__ __launch_bounds__(512) void k_fill(const int* __restrict__ row,
                                              const int* __restrict__ col, int E,
                                              int* cnt, int* __restrict__ ebuf,
                                              int NCB) {
    __shared__ int hcnt[NCB_MAX];   // per-bucket count, then scatter cursor
    __shared__ int lexcl[NCB_MAX];  // block-local exclusive offsets
    __shared__ int hbase[NCB_MAX];  // reserved global base per bucket
    __shared__ int part[NCB_MAX];
    __shared__ int sorted[EPB];
    int t = threadIdx.x;
    int e0 = blockIdx.x * EPB;
    int nloc = min(EPB, E - e0);
    if (t < NCB_MAX) hcnt[t] = 0;
    __syncthreads();

    int rr[16], cc[16];
#pragma unroll
    for (int k = 0; k < 4; k++) {
        int base = t * 4 + k * 2048;
        if (base + 3 < nloc) {
            int4 r4 = *(const int4*)(row + e0 + base);
            int4 c4 = *(const int4*)(col + e0 + base);
            rr[k * 4 + 0] = r4.x; rr[k * 4 + 1] = r4.y;
            rr[k * 4 + 2] = r4.z; rr[k * 4 + 3] = r4.w;
            cc[k * 4 + 0] = c4.x; cc[k * 4 + 1] = c4.y;
            cc[k * 4 + 2] = c4.z; cc[k * 4 + 3] = c4.w;
        } else {
#pragma unroll
            for (int q = 0; q < 4; q++) {
                int e = base + q;
                rr[k * 4 + q] = (e < nloc) ? row[e0 + e] : -1;
                cc[k * 4 + q] = (e < nloc) ? col[e0 + e] : 0;
            }
        }
    }
#pragma unroll
    for (int q = 0; q < 16; q++)
        if (rr[q] >= 0) atomicAdd(&hcnt[rr[q] >> CB_SHIFT], 1);
    __syncthreads();
    int myv = hcnt[t];
    part[t] = myv;
    __syncthreads();
    for (int off = 1; off < NCB_MAX; off <<= 1) {
        int a = (t >= off) ? part[t - off] : 0;
        __syncthreads();
        part[t] += a;
        __syncthreads();
    }
    lexcl[t] = part[t] - myv;
    hbase[t] = (myv > 0) ? atomicAdd(&cnt[t * CNT_STRIDE], myv) : 0;
    hcnt[t] = 0;  // reset as cursor
    __syncthreads();
#pragma unroll
    for (int q = 0; q < 16; q++) {
        int r = rr[q];
        if (r >= 0) {
            int cb = r >> CB_SHIFT;
            int p = lexcl[cb] + atomicAdd(&hcnt[cb], 1);
            sorted[p] = ((r & (CB_ROWS - 1)) << COL_BITS) | cc[q];
        }
    }
    __syncthreads();
    int wv = t >> 6, lane = t & 63;
    for (int cb = wv; cb < NCB; cb += 8) {
        int c = hcnt[cb];
        int ls = lexcl[cb];
        int* dst = ebuf + (size_t)cb * CAPCB + hbase[cb];
        for (int j = lane; j < c; j += 64) dst[j] = sorted[ls + j];
    }
}

// ---- pass B: exclusive scan of bucket totals -> global CSR bases ----
__global__ __launch_bounds__(512) void k_scan2(const int* __restrict__ cnt, int NCB,
                                               int* __restrict__ sbbase) {
    __shared__ int part[NCB_MAX];
    int t = threadIdx.x;
    int v = (t < NCB) ? cnt[t * CNT_STRIDE] : 0;
    part[t] = v;
    __syncthreads();
    for (int off = 1; off < NCB_MAX; off <<= 1) {
        int a = (t >= off) ? part[t - off] : 0;
        __syncthreads();
        part[t] += a;
        __syncthreads();
    }
    if (t < NCB) sbbase[t] = part[t] - v;
}

// ---- pass C: per-bucket counting sort fully in LDS; coalesced colsort writes ----
__global__ __launch_bounds__(256) void k_sort(const int* __restrict__ cnt,
                                              const int* __restrict__ sbbase,
                                              const int* __restrict__ ebuf, int n,
                                              int* __restrict__ colsort,
                                              int* __restrict__ deg,
                                              int* __restrict__ rs,
                                              float* __restrict__ dinv) {
    __shared__ int rcnt[CB_ROWS];
    __shared__ int rexcl[CB_ROWS];
    __shared__ int sorted[CAPCB];
    int cb = blockIdx.x;
    int t = threadIdx.x;
    int c = cnt[cb * CNT_STRIDE];
    const int* seg = ebuf + (size_t)cb * CAPCB;
    rcnt[t] = 0;
    __syncthreads();
    for (int base = t * 4; base < c; base += 1024) {
        if (base + 3 < c) {
            int4 v = *(const int4*)(seg + base);
            atomicAdd(&rcnt[v.x >> COL_BITS], 1);
            atomicAdd(&rcnt[v.y >> COL_BITS], 1);
            atomicAdd(&rcnt[v.z >> COL_BITS], 1);
            atomicAdd(&rcnt[v.w >> COL_BITS], 1);
        } else {
            for (int k = base; k < c; k++) atomicAdd(&rcnt[seg[k] >> COL_BITS], 1);
        }
    }
    __syncthreads();
    int myc = rcnt[t];
    rexcl[t] = myc;
    __syncthreads();
    for (int off = 1; off < CB_ROWS; off <<= 1) {
        int a = (t >= off) ? rexcl[t - off] : 0;
        __syncthreads();
        rexcl[t] += a;
        __syncthreads();
    }
    int excl = rexcl[t] - myc;
    int gbase = sbbase[cb];
    int i = (cb << CB_SHIFT) + t;
    if (i < n) {
        deg[i] = myc;
        rs[i] = gbase + excl;
        dinv[i] = rsqrtf((float)(myc + 1));
    }
    rcnt[t] = excl;  // reuse as cursor
    __syncthreads();
    for (int base = t * 4; base < c; base += 1024) {
        if (base + 3 < c) {
            int4 v = *(const int4*)(seg + base);
            int p0 = atomicAdd(&rcnt[v.x >> COL_BITS], 1); sorted[p0] = v.x & CMASK;
            int p1 = atomicAdd(&rcnt[v.y >> COL_BITS], 1); sorted[p1] = v.y & CMASK;
            int p2 = atomicAdd(&rcnt[v.z >> COL_BITS], 1); sorted[p2] = v.z & CMASK;
            int p3 = atomicAdd(&rcnt[v.w >> COL_BITS], 1); sorted[p3] = v.w & CMASK;
        } else {
            for (int k = base; k < c; k++) {
                int v = seg[k];
                int p = atomicAdd(&rcnt[v >> COL_BITS], 1);
                sorted[p] = v & CMASK;
            }
        }
    }
    __syncthreads();
    for (int j = t; j < c; j += 256) colsort[gbase + j] = sorted[j];
}

// ---------------- GEMM1: hp[i][j] = fp16( dinv[i] * (x[i,:] @ W1[:,j]) ) --------
__global__ __launch_bounds__(256, 2) void k_gemm1(const float* __restrict__ x,
                                                  const float* __restrict__ W1,
                                                  const float* __restrict__ dinv,
                                                  __half* __restrict__ hp, int n,
                                                  int total_waves) {
    int lane = threadIdx.x & 63;
    int wid = blockIdx.x * (blockDim.x >> 6) + (threadIdx.x >> 6);

    float w[8][16];
#pragma unroll
    for (int h = 0; h < 2; h++) {
#pragma unroll
        for (int r = 0; r < 4; r++) {
            int k = h * 256 + 4 * lane + r;
            const float4* p = (const float4*)(W1 + k * 16);
            float4 a = p[0], b = p[1], c = p[2], d = p[3];
            float* wr = w[h * 4 + r];
            wr[0] = a.x; wr[1] = a.y; wr[2] = a.z; wr[3] = a.w;
            wr[4] = b.x; wr[5] = b.y; wr[6] = b.z; wr[7] = b.w;
            wr[8] = c.x; wr[9] = c.y; wr[10] = c.z; wr[11] = c.w;
            wr[12] = d.x; wr[13] = d.y; wr[14] = d.z; wr[15] = d.w;
        }
    }

    for (int i0 = wid * 4; i0 < n; i0 += total_waves * 4) {
        float4 xq[8];
        if (i0 + 3 < n) {
            const float4* xp = (const float4*)(x + (size_t)i0 * F0);
#pragma unroll
            for (int q = 0; q < 8; q++) xq[q] = xp[q * 64 + lane];
        } else {
#pragma unroll
            for (int q = 0; q < 8; q++) {
                int r = q >> 1;
                if (i0 + r < n) {
                    const float4* xp = (const float4*)(x + (size_t)(i0 + r) * F0);
                    xq[q] = xp[(q & 1) * 64 + lane];
                } else {
                    xq[q] = make_float4(0.f, 0.f, 0.f, 0.f);
                }
            }
        }
        bool b0 = (lane & 1) != 0;
        bool b1 = (lane & 2) != 0;
        bool b2 = (lane & 4) != 0;
        bool b3 = (lane & 8) != 0;
#pragma unroll
        for (int r = 0; r < 4; r++) {
            float4 xa = xq[2 * r], xb = xq[2 * r + 1];
            float v16[16];
#pragma unroll
            for (int j = 0; j < 16; j++) {
                v16[j] = xa.x * w[0][j] + xa.y * w[1][j] + xa.z * w[2][j] + xa.w * w[3][j]
                       + xb.x * w[4][j] + xb.y * w[5][j] + xb.z * w[6][j] + xb.w * w[7][j];
            }
            float v8[8];
#pragma unroll
            for (int t2 = 0; t2 < 8; t2++) {
                float a = v16[2 * t2], b = v16[2 * t2 + 1];
                float keep = b0 ? b : a;
                float send = b0 ? a : b;
                v8[t2] = keep + __shfl_xor(send, 1);
            }
            float v4[4];
#pragma unroll
            for (int t2 = 0; t2 < 4; t2++) {
                float a = v8[2 * t2], b = v8[2 * t2 + 1];
                float keep = b1 ? b : a;
                float send = b1 ? a : b;
                v4[t2] = keep + __shfl_xor(send, 2);
            }
            float v2[2];
#pragma unroll
            for (int t2 = 0; t2 < 2; t2++) {
                float a = v4[2 * t2], b = v4[2 * t2 + 1];
                float keep = b2 ? b : a;
                float send = b2 ? a : b;
                v2[t2] = keep + __shfl_xor(send, 4);
            }
            float keep = b3 ? v2[1] : v2[0];
            float send = b3 ? v2[0] : v2[1];
            float v1 = keep + __shfl_xor(send, 8);
            v1 += __shfl_xor(v1, 16);
            v1 += __shfl_xor(v1, 32);
            int i = i0 + r;
            if (lane < 16 && i < n)
                hp[(size_t)i * F1 + lane] = __float2half_rn(dinv[i] * v1);
        }
    }
}

// ---------------- SpMM1 + relu, store s2 = fp16(dinv * h1) (16 feats) ----------
// 4 lanes per row (lane owns 4 feats via one 8B load): 16 rows/wave, 8-deep
// unroll -> 128 gathers in flight per wave.
__global__ __launch_bounds__(256) void k_spmm1(const __half* __restrict__ hp,
                                               const int* __restrict__ rs,
                                               const int* __restrict__ deg,
                                               const int* __restrict__ colsort,
                                               const float* __restrict__ dinv,
                                               const float* __restrict__ b1,
                                               __half* __restrict__ s2, int n) {
    int t = threadIdx.x;
    int jq = t & 3;                       // features 4jq..4jq+3
    int i = blockIdx.x * 64 + (t >> 2);
    if (i >= n) return;
    int s = rs[i], c = deg[i];
    const int* cs = colsort + s;

    float4 acc;
    {   // self loop
        float2 r = *(const float2*)(hp + (size_t)i * F1 + 4 * jq);
        __half2 h01 = *(__half2*)&r.x;
        __half2 h23 = *(__half2*)&r.y;
        float2 f01 = __half22float2(h01), f23 = __half22float2(h23);
        acc = make_float4(f01.x, f01.y, f23.x, f23.y);
    }
    int e = 0;
    for (; e + 7 < c; e += 8) {
        int cc[8];
#pragma unroll
        for (int q = 0; q < 8; q++) cc[q] = cs[e + q];
        float2 rr[8];
#pragma unroll
        for (int q = 0; q < 8; q++)
            rr[q] = *(const float2*)(hp + (size_t)cc[q] * F1 + 4 * jq);
#pragma unroll
        for (int q = 0; q < 8; q++) {
            __half2 h01 = *(__half2*)&rr[q].x;
            __half2 h23 = *(__half2*)&rr[q].y;
            float2 f01 = __half22float2(h01), f23 = __half22float2(h23);
            acc.x += f01.x; acc.y += f01.y; acc.z += f23.x; acc.w += f23.y;
        }
    }
    for (; e < c; e++) {
        float2 r = *(const float2*)(hp + (size_t)cs[e] * F1 + 4 * jq);
        __half2 h01 = *(__half2*)&r.x;
        __half2 h23 = *(__half2*)&r.y;
        float2 f01 = __half22float2(h01), f23 = __half22float2(h23);
        acc.x += f01.x; acc.y += f01.y; acc.z += f23.x; acc.w += f23.y;
    }
    float di = dinv[i];
    float4 bb = *(const float4*)(b1 + 4 * jq);
    float h0 = fmaxf(di * acc.x + bb.x, 0.f);
    float h1 = fmaxf(di * acc.y + bb.y, 0.f);
    float h2 = fmaxf(di * acc.z + bb.z, 0.f);
    float h3 = fmaxf(di * acc.w + bb.w, 0.f);
    float2 ov;
    *(__half2*)&ov.x = __floats2half2_rn(di * h0, di * h1);
    *(__half2*)&ov.y = __floats2half2_rn(di * h2, di * h3);
    *(float2*)(s2 + (size_t)i * F1 + 4 * jq) = ov;
}

// ---------------- SpMM2 (16 feats) + GEMM2 + bias + log_softmax ----------------
// 8 lanes per row (lane owns 2 feats via __half2): 8 rows/wave, 64 gathers in
// flight. Epilogue: lane jh computes out cols {jh+8q, q=0..4}; width-8 softmax.
__global__ __launch_bounds__(256) void k_spmm2(const __half* __restrict__ s2,
                                               const int* __restrict__ rs,
                                               const int* __restrict__ deg,
                                               const int* __restrict__ colsort,
                                               const float* __restrict__ dinv,
                                               const float* __restrict__ W2,
                                               const float* __restrict__ b2,
                                               float* __restrict__ out, int n) {
    __shared__ float sW2[F1 * F2];
    int t = threadIdx.x;
    for (int idx = t; idx < F1 * F2; idx += 256) sW2[idx] = W2[idx];
    __syncthreads();

    int jh = t & 7;                       // features 2jh, 2jh+1
    int i = blockIdx.x * 32 + (t >> 3);
    if (i >= n) return;
    int s = rs[i], c = deg[i];
    const int* cs = colsort + s;
    float2 acc = __half22float2(*(const __half2*)(s2 + (size_t)i * F1 + 2 * jh));
    int e = 0;
    for (; e + 7 < c; e += 8) {
        int cc[8];
#pragma unroll
        for (int q = 0; q < 8; q++) cc[q] = cs[e + q];
        __half2 hh[8];
#pragma unroll
        for (int q = 0; q < 8; q++)
            hh[q] = *(const __half2*)(s2 + (size_t)cc[q] * F1 + 2 * jh);
#pragma unroll
        for (int q = 0; q < 8; q++) {
            float2 f = __half22float2(hh[q]);
            acc.x += f.x; acc.y += f.y;
        }
    }
    for (; e < c; e++) {
        float2 f = __half22float2(*(const __half2*)(s2 + (size_t)cs[e] * F1 + 2 * jh));
        acc.x += f.x; acc.y += f.y;
    }
    float di = dinv[i];
    float zx0 = di * acc.x, zy0 = di * acc.y;

    float o[5] = {0.f, 0.f, 0.f, 0.f, 0.f};
#pragma unroll
    for (int sl = 0; sl < 8; sl++) {
        float zx = __shfl(zx0, sl, 8);
        float zy = __shfl(zy0, sl, 8);
#pragma unroll
        for (int q = 0; q < 5; q++) {
            int k = jh + 8 * q;
            o[q] += zx * sW2[(2 * sl) * F2 + k] + zy * sW2[(2 * sl + 1) * F2 + k];
        }
    }
    float v[5];
    float m = -INFINITY;
#pragma unroll
    for (int q = 0; q < 5; q++) {
        v[q] = o[q] + b2[jh + 8 * q];
        m = fmaxf(m, v[q]);
    }
#pragma unroll
    for (int off = 1; off < 8; off <<= 1) m = fmaxf(m, __shfl_xor(m, off, 8));
    float ssum = 0.f;
#pragma unroll
    for (int q = 0; q < 5; q++) ssum += __expf(v[q] - m);
#pragma unroll
    for (int off = 1; off < 8; off <<= 1) ssum += __shfl_xor(ssum, off, 8);
    float lse = m + __logf(ssum);
    float* orow = out + (size_t)i * F2;
#pragma unroll
    for (int q = 0; q < 5; q++) orow[jh + 8 * q] = v[q] - lse;
}

extern "C" void kernel_launch(void* const* d_in, const int* in_sizes, int n_in,
                              void* d_out, int out_size, void* d_ws, size_t ws_size,
                              hipStream_t stream) {
    const float* x  = (const float*)d_in[0];
    const float* W1 = (const float*)d_in[1];
    const float* b1 = (const float*)d_in[2];
    const float* W2 = (const float*)d_in[3];
    const float* b2 = (const float*)d_in[4];
    const int*   ei = (const int*)d_in[5];

    int n = in_sizes[0] / F0;
    int E = in_sizes[5] / 2;
    const int* row = ei;
    const int* col = ei + E;
    int NCB = (n + CB_ROWS - 1) >> CB_SHIFT;   // 391 for n=100000

    // workspace carve-up (4-byte elements)
    int* deg     = (int*)d_ws;                 // n
    int* rs      = deg + n;                    // n
    float* dinv  = (float*)(rs + n);           // n
    int* cnt     = (int*)(dinv + n);           // NCB_MAX*CNT_STRIDE
    int* sbbase  = cnt + NCB_MAX * CNT_STRIDE; // NCB_MAX
    int* colsort = sbbase + NCB_MAX;           // E
    int* ebuf    = colsort + E;                // NCB*CAPCB (~14.4 MB), dead after k_sort
    __half* hp   = (__half*)ebuf;              // n x 16 fp16 (overlay, 3.2 MB)
    __half* s2   = hp + (size_t)n * F1;        // n x 16 fp16 (overlay, 3.2 MB)

    int nchunks = (E + EPB - 1) / EPB;         // 391
    k_zero<<<(NCB * CNT_STRIDE + 255) / 256, 256, 0, stream>>>(cnt, NCB * CNT_STRIDE);
    k_fill<<<nchunks, 512, 0, stream>>>(row, col, E, cnt, ebuf, NCB);
    k_scan2<<<1, NCB_MAX, 0, stream>>>(cnt, NCB, sbbase);
    k_sort<<<NCB, 256, 0, stream>>>(cnt, sbbase, ebuf, n, colsort, deg, rs, dinv);

    int g1_blocks = 2048;
    k_gemm1<<<g1_blocks, 256, 0, stream>>>(x, W1, dinv, hp, n, g1_blocks * 4);
    k_spmm1<<<(n + 63) / 64, 256, 0, stream>>>(hp, rs, deg, colsort, dinv, b1, s2, n);
    k_spmm2<<<(n + 31) / 32, 256, 0, stream>>>(s2, rs, deg, colsort, dinv, W2, b2,
                                               (float*)d_out, n);
}